// Round 9
// baseline (1252.215 us; speedup 1.0000x reference)
//
#include <hip/hip_runtime.h>
#include <hip/hip_bf16.h>

typedef __attribute__((ext_vector_type(8))) short short8;
typedef __attribute__((ext_vector_type(4))) float f32x4;

// B=4096, S=64, V=50000, D=300, H=6, E=400, VS=200, DH=50
// ws layout (u16 elems): MFMA B-frag jobs, 512 elems per (tn,kt) tile:
// elem(lane,i) = W[k][n], n = tn*16+(lane&15), k = kt*32+(lane>>4)*8+i
#define KF 0             // 19 jobs Wk          [19][10][512]
#define VF 97280         // 19 jobs Wv
#define CQF 194560       // 1 job: cols 0-5 = cq_h = Wq[:,blk]@wq_attn_h
#define WQ1 199680       // 19 jobs Wq (for T1 g-GEMM)
#define OFC 296960       // 19 jobs x 20kt [Wqo ; Wro]  (Wqo=Wq@Wo, Wro=Wr@Wo)
#define PFW 491520       // 25 jobs Wp
#define AFW 619520       // 13 jobs x 13kt Wa
#define BOBF 706048      // float[304]: bo + br@Wo
#define PREP_TOTAL 706656

#define MFMA(a, b, c) __builtin_amdgcn_mfma_f32_16x16x32_bf16((a), (b), (c), 0, 0, 0)

__device__ __forceinline__ unsigned short f2b(float f) {
  unsigned int u = __builtin_bit_cast(unsigned int, f);
  u += 0x7FFFu + ((u >> 16) & 1u);
  return (unsigned short)(u >> 16);
}
__device__ __forceinline__ float b2f(unsigned short h) {
  unsigned int u = ((unsigned int)h) << 16;
  return __builtin_bit_cast(float, u);
}

__global__ void prep_weights(const float* __restrict__ Wq, const float* __restrict__ Wk,
                             const float* __restrict__ Wv, const float* __restrict__ Wr,
                             const float* __restrict__ Wo, const float* __restrict__ Wp,
                             const float* __restrict__ Wa, const float* __restrict__ wq_attn,
                             const float* __restrict__ br, const float* __restrict__ bo,
                             unsigned short* __restrict__ ws) {
  int idx = blockIdx.x * blockDim.x + threadIdx.x;
  if (idx >= PREP_TOTAL) return;
  if (idx >= BOBF) {
    int n = idx - BOBF;
    if (n >= 304) return;
    float s = 0.f;
    if (n < 300) {
      s = bo[n];
      for (int m = 0; m < 300; ++m) s += br[m % 50] * Wo[m * 300 + n];
    }
    ((float*)(ws))[BOBF / 2 + n] = s;
    return;
  }
  float val = 0.f;
  if (idx < CQF) {                        // Wk / Wv plain
    int m = idx / 97280, local = idx % 97280;
    int tn = local / 5120, r = local % 5120;
    int kt = r / 512; r &= 511;
    int lane = r >> 3, i = r & 7;
    int n = tn * 16 + (lane & 15), k = kt * 32 + (lane >> 4) * 8 + i;
    if (n < 300 && k < 300) val = (m == 0) ? Wk[k * 300 + n] : Wv[k * 300 + n];
  } else if (idx < WQ1) {                 // cq job
    int local = idx - CQF;
    int kt = local / 512, r = local & 511;
    int lane = r >> 3, i = r & 7;
    int n = lane & 15, k = kt * 32 + (lane >> 4) * 8 + i;
    if (n < 6 && k < 300) {
      float s = 0.f;
      for (int d = 0; d < 50; ++d) s += Wq[k * 300 + 50 * n + d] * wq_attn[n * 50 + d];
      val = s;
    }
  } else if (idx < OFC) {                 // Wq plain (T1)
    int local = idx - WQ1;
    int tn = local / 5120, r = local % 5120;
    int kt = r / 512; r &= 511;
    int lane = r >> 3, i = r & 7;
    int n = tn * 16 + (lane & 15), k = kt * 32 + (lane >> 4) * 8 + i;
    if (n < 300 && k < 300) val = Wq[k * 300 + n];
  } else if (idx < PFW) {                 // [Wqo ; Wro] 20kt
    int local = idx - OFC;
    int tn = local / 10240, r = local % 10240;
    int kt = r / 512; r &= 511;
    int lane = r >> 3, i = r & 7;
    int n = tn * 16 + (lane & 15), kk = (lane >> 4) * 8 + i;
    if (n < 300) {
      if (kt < 10) {
        int k = kt * 32 + kk;
        if (k < 300) {                    // Wqo[k][n] = sum_j Wq[k][j] Wo[j][n]
          float s = 0.f;
          for (int j = 0; j < 300; ++j) s += Wq[k * 300 + j] * Wo[j * 300 + n];
          val = s;
        }
      } else {
        int k = (kt - 10) * 32 + kk;
        if (k < 300) {                    // Wro[k][n] = sum_j Wr[k%50][j] Wo[50*(k/50)+j][n]
          int h = k / 50, i2 = k % 50;
          float s = 0.f;
          for (int j = 0; j < 50; ++j) s += Wr[i2 * 50 + j] * Wo[(50 * h + j) * 300 + n];
          val = s;
        }
      }
    }
  } else if (idx < AFW) {                 // Wp
    int local = idx - PFW;
    int tn = local / 5120, r = local % 5120;
    int kt = r / 512; r &= 511;
    int lane = r >> 3, i = r & 7;
    int n = tn * 16 + (lane & 15), k = kt * 32 + (lane >> 4) * 8 + i;
    if (k < 300) val = Wp[k * 400 + n];
  } else {                                // Wa 13kt
    int local = idx - AFW;
    int tn = local / 6656, r = local % 6656;
    int kt = r / 512; r &= 511;
    int lane = r >> 3, i = r & 7;
    int n = tn * 16 + (lane & 15), k = kt * 32 + (lane >> 4) * 8 + i;
    if (n < 200 && k < 400) val = Wa[k * 200 + n];
  }
  ws[idx] = f2b(val);
}

// LDS layout (bytes)
#define MISCB 0       // float[1440]: aM[6][64] g[304] gw[304] gkf[320] scp[64] wsm[64]
#define TB 5760       // bf16 [16][312] + 32B zero pad (T matrix for T1)
#define XB 15872      // ushort [64][312] x ; later h cols 0-311
#define KB 55808      // ushort [64][312] K ; later attn_out
#define VB 95744      // ushort [64][312] v -> u ; head = h side cols 312-415 [64][104]
#define STGB 135680   // 20480 B weight staging
#define SMEM_BYTES 156224
#define STR 312

struct PFR { short8 r[4]; };
__device__ __forceinline__ int pf_load(PFR& p, const unsigned short* a, int ca,
                                       const unsigned short* b, int cb, int tid) {
  int tot = ca + cb;
#pragma unroll
  for (int i = 0; i < 4; ++i) {
    int idx = tid + i * 512;
    if (idx < tot) {
      const unsigned short* src = (idx < ca) ? (a + (size_t)idx * 8) : (b + (size_t)(idx - ca) * 8);
      p.r[i] = *(const short8*)src;
    }
  }
  return tot;
}
__device__ __forceinline__ void pf_commit(const PFR& p, unsigned short* stg, int tot, int tid) {
#pragma unroll
  for (int i = 0; i < 4; ++i) {
    int idx = tid + i * 512;
    if (idx < tot) *(short8*)(stg + idx * 8) = p.r[i];
  }
}

__device__ __forceinline__ f32x4 chain10(const short8* a, const unsigned short* bp) {
  f32x4 c0 = {0.f, 0.f, 0.f, 0.f}, c1 = c0;
#pragma unroll
  for (int k = 0; k < 10; k += 2) {
    short8 b0 = *(const short8*)(bp + k * 512);
    short8 b1 = *(const short8*)(bp + (k + 1) * 512);
    c0 = MFMA(a[k], b0, c0);
    c1 = MFMA(a[k + 1], b1, c1);
  }
  return c0 + c1;
}

__global__ __launch_bounds__(512, 1) void doc_encoder(
    const int* __restrict__ tokens, const float* __restrict__ emb,
    const float* __restrict__ wk_attn, const float* __restrict__ bp_,
    const float* __restrict__ ba_, const float* __restrict__ va_,
    const unsigned short* __restrict__ ws, float* __restrict__ out) {
  __shared__ alignas(16) unsigned char smem[SMEM_BYTES];
  float* miscf = (float*)(smem + MISCB);
  unsigned short* Tm = (unsigned short*)(smem + TB);
  unsigned short* xb = (unsigned short*)(smem + XB);
  unsigned short* kb = (unsigned short*)(smem + KB);
  unsigned short* vb = (unsigned short*)(smem + VB);
  unsigned short* stg = (unsigned short*)(smem + STGB);
  unsigned short* hb = xb;                         // h cols 0-311 overlay
  unsigned short* side = vb;                       // h cols 312-415 [64][104] overlay
  float* gB = miscf + 384;    // [304]
  float* gw = miscf + 688;    // [304]
  float* gkf = miscf + 992;   // [320]
  float* scp = miscf + 1312;  // [64]
  float* wsm = miscf + 1376;  // [64]

  const int b = blockIdx.x;
  const int tid = threadIdx.x;
  const int lane = tid & 63;
  const int wv = tid >> 6;     // 0..7
  const int wm = wv & 3;       // M tile
  const int wn = wv >> 2;      // N pair
  const int l15 = lane & 15;
  const int lg = lane >> 4;
  const int kofs = lg * 8;
  const int arow = wm * 16 + l15;
  const int cr0 = wm * 16 + lg * 4;
  const float* bobf = ((const float*)ws) + BOBF / 2;
  const float scale = 0.1414213562373095f;

  PFR pf;
  int ptot = pf_load(pf, ws + KF, 1280, ws + KF, 0, tid);   // phase-B chunk 0

  // ---- zero inits ----
  for (int i = tid; i < 5008; i += 512) Tm[i] = 0;          // T + tail pad
  for (int i = tid; i < 64 * 12; i += 512) {
    int s = i / 12, c = 300 + i % 12;
    kb[s * STR + c] = 0; vb[s * STR + c] = 0;
  }
  if (tid < 20) gkf[300 + tid] = 0.f;
  if (tid < 8) kb[tid] = 0;                                 // xb row63 over-read target

  // ---- gather x = emb[tokens[b]] -> xb bf16 [64][312] ----
  for (int i = tid; i < 64 * 39; i += 512) {
    int s = i / 39, c8 = (i % 39) * 8;
    int tok = tokens[b * 64 + s];
    const float* rp = emb + (size_t)tok * 300;
    short8 v;
    if (c8 + 8 <= 300) {
      f32x4 u0 = *(const f32x4*)(rp + c8);
      f32x4 u1 = *(const f32x4*)(rp + c8 + 4);
#pragma unroll
      for (int j = 0; j < 4; ++j) { v[j] = (short)f2b(u0[j]); v[4 + j] = (short)f2b(u1[j]); }
    } else {
#pragma unroll
      for (int j = 0; j < 8; ++j) v[j] = (c8 + j < 300) ? (short)f2b(rp[c8 + j]) : (short)0;
    }
    *(short8*)&xb[s * STR + c8] = v;
  }
  __syncthreads();   // B0: gather done, STG free

  short8 ax[10];
#pragma unroll
  for (int kt = 0; kt < 10; ++kt)
    ax[kt] = *(const short8*)&xb[arow * STR + kt * 32 + kofs];

  // ======== Phase B: K(19) V(19) cq(1) = 39 jobs, chunks of 2 ========
  for (int c = 0; c < 20; ++c) {
    pf_commit(pf, stg, ptot, tid);
    if (c + 1 < 20) {
      int cnt = (c + 1 == 19) ? 640 : 1280;
      ptot = pf_load(pf, ws + KF + (size_t)(c + 1) * 10240, cnt, ws + KF, 0, tid);
    }
    __syncthreads();
    int j = 2 * c + wn;
    if (j < 39) {
      const unsigned short* bp = stg + wn * 5120 + lane * 8;
      f32x4 a = chain10(ax, bp);
      if (j < 19) {
        int n = j * 16 + l15;
        if (n < 300) {
#pragma unroll
          for (int r = 0; r < 4; ++r) kb[(cr0 + r) * STR + n] = f2b(a[r]);
        }
      } else if (j < 38) {
        int n = (j - 19) * 16 + l15;
        if (n < 300) {
#pragma unroll
          for (int r = 0; r < 4; ++r) vb[(cr0 + r) * STR + n] = f2b(a[r]);
        }
      } else if (l15 < 6) {
#pragma unroll
        for (int r = 0; r < 4; ++r) miscf[l15 * 64 + cr0 + r] = a[r] * scale;
      }
    }
    __syncthreads();
  }

  ptot = pf_load(pf, ws + WQ1, 1280, ws + WQ1, 0, tid);     // T1 chunk 0

  // ---- alpha softmax (wave h) ----
  if (wv < 6) {
    float* aMh = miscf + wv * 64;
    float x = aMh[lane];
    float m = x;
#pragma unroll
    for (int off = 32; off; off >>= 1) m = fmaxf(m, __shfl_xor(m, off));
    float e = __expf(x - m);
    float ss = e;
#pragma unroll
    for (int off = 32; off; off >>= 1) ss += __shfl_xor(ss, off);
    aMh[lane] = e / ss;
  }
  __syncthreads();

  // ---- t_alpha = alpha^T x  -> T rows 0..5 (bf16) ----
  {
    int c = wv * 38 + lane;
    if (lane < 38 && c < 300) {
      float acc[6] = {0.f, 0.f, 0.f, 0.f, 0.f, 0.f};
      for (int s = 0; s < 64; ++s) {
        float xv = b2f(xb[s * STR + c]);
#pragma unroll
        for (int h = 0; h < 6; ++h) acc[h] += miscf[h * 64 + s] * xv;
      }
#pragma unroll
      for (int h = 0; h < 6; ++h) Tm[h * STR + c] = f2b(acc[h]);
    }
  }
  __syncthreads();

  // ======== T1: g = t_alpha @ Wq (19 jobs M=16, chunks of 2) ========
  {
    short8 aT[10];
#pragma unroll
    for (int kt = 0; kt < 10; ++kt)
      aT[kt] = *(const short8*)&Tm[l15 * STR + kt * 32 + kofs];
    for (int c = 0; c < 10; ++c) {
      pf_commit(pf, stg, ptot, tid);
      if (c + 1 < 10) {
        int cnt = (c + 1 == 9) ? 640 : 1280;
        ptot = pf_load(pf, ws + WQ1 + (size_t)(c + 1) * 10240, cnt, ws + WQ1, 0, tid);
      }
      __syncthreads();
      int j = 2 * c + wn;
      if (wm == 0 && j < 19) {
        const unsigned short* bp = stg + wn * 5120 + lane * 8;
        f32x4 a = chain10(aT, bp);
        int dt = j * 16 + l15;
#pragma unroll
        for (int r = 0; r < 4; ++r) {
          int h = lg * 4 + r;
          if (h < 6 && dt >= 50 * h && dt < 50 * h + 50) gB[dt] = a[r];
        }
      }
      __syncthreads();
    }
  }
  if (tid < 300) gw[tid] = gB[tid] * wk_attn[tid];
  __syncthreads();

  // ---- beta softmax (wave h) ----
  if (wv < 6) {
    const int h = wv;
    float* aMh = miscf + h * 64;
    float p = 0.f;
    const unsigned short* krow = kb + lane * STR + 50 * h;
    for (int dd = 0; dd < 50; ++dd) p += gw[50 * h + dd] * b2f(krow[dd]);
    p *= scale;
    float m = p;
#pragma unroll
    for (int off = 32; off; off >>= 1) m = fmaxf(m, __shfl_xor(m, off));
    float e = __expf(p - m);
    float ss = e;
#pragma unroll
    for (int off = 32; off; off >>= 1) ss += __shfl_xor(ss, off);
    aMh[lane] = e / ss;
  }
  __syncthreads();
  // ---- gk = g o (beta^T k) ----
  if (wv < 6 && lane < 50) {
    const int h = wv;
    float gks = 0.f;
    const unsigned short* kcol = kb + 50 * h + lane;
    for (int s = 0; s < 64; ++s) gks += miscf[h * 64 + s] * b2f(kcol[s * STR]);
    gkf[50 * h + lane] = gB[50 * h + lane] * gks;
  }
  __syncthreads();

  ptot = pf_load(pf, ws + OFC, 640, ws + OFC + 10240, 640, tid);  // attn chunk (0,0)

  // ---- u = gk o v in-place in vb ----
  for (int i = tid; i < 64 * 39; i += 512) {
    int s = i / 39, c8 = (i % 39) * 8;
    short8 vf = *(const short8*)&vb[s * STR + c8];
    short8 uf;
#pragma unroll
    for (int j = 0; j < 8; ++j) {
      int c = c8 + j;
      uf[j] = (c < 300) ? (short)f2b(gkf[c] * b2f((unsigned short)vf[j])) : (short)0;
    }
    *(short8*)&vb[s * STR + c8] = uf;
  }
  __syncthreads();

  // ======== attn_out = x@Wqo + u@Wro + bobf -> kb  (10 pairs x 2 halves) ========
  {
    f32x4 acc = {0.f, 0.f, 0.f, 0.f};
    for (int t = 0; t < 20; ++t) {
      pf_commit(pf, stg, ptot, tid);
      if (t + 1 < 20) {
        int nc = (t + 1) >> 1, np = (t + 1) & 1;
        const unsigned short* A = ws + OFC + (size_t)(2 * nc) * 10240 + np * 5120;
        const unsigned short* Bp = A;
        int cb = 0;
        if (2 * nc + 1 < 19) { Bp = ws + OFC + (size_t)(2 * nc + 1) * 10240 + np * 5120; cb = 640; }
        ptot = pf_load(pf, A, 640, Bp, cb, tid);
      }
      __syncthreads();
      int c = t >> 1, p = t & 1;
      int j = 2 * c + wn;
      if (j < 19) {
        const unsigned short* bp = stg + wn * 5120 + lane * 8;
        if (p == 0) {
          acc = chain10(ax, bp);
        } else {
#pragma unroll
          for (int k = 0; k < 10; ++k) {
            short8 a = *(const short8*)&vb[arow * STR + k * 32 + kofs];
            short8 bt = *(const short8*)(bp + k * 512);
            acc = MFMA(a, bt, acc);
          }
          int n = j * 16 + l15;
          if (n < 300) {
            float bias = bobf[n];
#pragma unroll
            for (int r = 0; r < 4; ++r) kb[(cr0 + r) * STR + n] = f2b(acc[r] + bias);
          }
        }
      }
      __syncthreads();
    }
  }

  ptot = pf_load(pf, ws + PFW, 1280, ws + PFW, 0, tid);     // Wp chunk 0

  // zero side pad cols 88..103 (h cols 400-415); u dead
  for (int i = tid; i < 64 * 16; i += 512) side[(i >> 4) * 104 + 88 + (i & 15)] = 0;

  // ======== h = attn_out @ Wp + bp -> hb[312] + side[104]  (13 chunks of 2) ========
  {
    short8 ao[10];
#pragma unroll
    for (int kt = 0; kt < 10; ++kt)
      ao[kt] = *(const short8*)&kb[arow * STR + kt * 32 + kofs];
    for (int c = 0; c < 13; ++c) {
      pf_commit(pf, stg, ptot, tid);
      if (c + 1 < 13) {
        int cnt = (c + 1 == 12) ? 640 : 1280;
        ptot = pf_load(pf, ws + PFW + (size_t)(c + 1) * 10240, cnt, ws + PFW, 0, tid);
      }
      __syncthreads();
      int j = 2 * c + wn;
      if (j < 25) {
        const unsigned short* bp = stg + wn * 5120 + lane * 8;
        f32x4 a = chain10(ao, bp);
        int n = j * 16 + l15;
        float bias = bp_[n];
#pragma unroll
        for (int r = 0; r < 4; ++r) {
          unsigned short val = f2b(a[r] + bias);
          if (n < 312) hb[(cr0 + r) * STR + n] = val;
          else side[(cr0 + r) * 104 + n - 312] = val;
        }
      }
      __syncthreads();
    }
  }

  ptot = pf_load(pf, ws + AFW, 832, ws + AFW, 0, tid);      // Wa chunk 0

  // ======== scores = tanh(h@Wa + ba) @ va  (13 chunks of 1, wn-duplicated) ========
  {
    short8 ah[13];
#pragma unroll
    for (int kt = 0; kt < 9; ++kt)
      ah[kt] = *(const short8*)&hb[arow * STR + kt * 32 + kofs];
    ah[9] = (lg < 3) ? *(const short8*)&hb[arow * STR + 288 + kofs]
                     : *(const short8*)&side[arow * 104];
    ah[10] = *(const short8*)&side[arow * 104 + 8 + kofs];
    ah[11] = *(const short8*)&side[arow * 104 + 40 + kofs];
    ah[12] = *(const short8*)&side[arow * 104 + 72 + kofs];
    float sp[4] = {0.f, 0.f, 0.f, 0.f};
    for (int c = 0; c < 13; ++c) {
      pf_commit(pf, stg, ptot, tid);
      if (c + 1 < 13)
        ptot = pf_load(pf, ws + AFW + (size_t)(c + 1) * 6656, 832, ws + AFW, 0, tid);
      __syncthreads();
      {
        const unsigned short* bp = stg + lane * 8;
        f32x4 c0 = {0.f, 0.f, 0.f, 0.f}, c1 = c0;
#pragma unroll
        for (int k = 0; k < 12; k += 2) {
          short8 b0 = *(const short8*)(bp + k * 512);
          short8 b1 = *(const short8*)(bp + (k + 1) * 512);
          c0 = MFMA(ah[k], b0, c0);
          c1 = MFMA(ah[k + 1], b1, c1);
        }
        c0 = MFMA(ah[12], *(const short8*)(bp + 12 * 512), c0);
        int n = c * 16 + l15;
        if (n < 200) {
          float ban = ba_[n], van = va_[n];
#pragma unroll
          for (int r = 0; r < 4; ++r) {
            float x0 = fminf(fmaxf(c0[r] + c1[r] + ban, -15.f), 15.f);
            float t0 = __expf(2.f * x0);
            sp[r] += (t0 - 1.f) / (t0 + 1.f) * van;
          }
        }
      }
      __syncthreads();
    }
#pragma unroll
    for (int off = 1; off < 16; off <<= 1) {
#pragma unroll
      for (int r = 0; r < 4; ++r) sp[r] += __shfl_xor(sp[r], off);
    }
    if (l15 == 0 && wn == 0) {
#pragma unroll
      for (int r = 0; r < 4; ++r) scp[cr0 + r] = sp[r];
    }
  }
  __syncthreads();
  if (wv == 0) {
    float x = scp[lane];
    float m = x;
#pragma unroll
    for (int off = 32; off; off >>= 1) m = fmaxf(m, __shfl_xor(m, off));
    float e = __expf(x - m);
    float ss = e;
#pragma unroll
    for (int off = 32; off; off >>= 1) ss += __shfl_xor(ss, off);
    wsm[lane] = e / ss;
  }
  __syncthreads();

  // ---- pooled[e] = sum_s wsm[s] h[s][e] ----
  if (tid < 400) {
    float a0 = 0.f, a1 = 0.f, a2 = 0.f, a3 = 0.f;
    for (int s = 0; s < 64; s += 4) {
#pragma unroll
      for (int q = 0; q < 4; ++q) {
        int sq = s + q;
        float hv = (tid < 312) ? b2f(hb[sq * STR + tid]) : b2f(side[sq * 104 + tid - 312]);
        if (q == 0) a0 += wsm[sq] * hv;
        else if (q == 1) a1 += wsm[sq] * hv;
        else if (q == 2) a2 += wsm[sq] * hv;
        else a3 += wsm[sq] * hv;
      }
    }
    out[(size_t)b * 400 + tid] = (a0 + a1) + (a2 + a3);
  }
}

extern "C" void kernel_launch(void* const* d_in, const int* in_sizes, int n_in,
                              void* d_out, int out_size, void* d_ws, size_t ws_size,
                              hipStream_t stream) {
  (void)in_sizes; (void)n_in; (void)out_size; (void)ws_size;
  const int* tokens = (const int*)d_in[0];
  const float* emb = (const float*)d_in[1];
  const float* Wq = (const float*)d_in[2];
  const float* Wk = (const float*)d_in[3];
  const float* Wv = (const float*)d_in[4];
  const float* wq_attn = (const float*)d_in[5];
  const float* wk_attn = (const float*)d_in[6];
  const float* Wr = (const float*)d_in[7];
  const float* br = (const float*)d_in[8];
  const float* Wo = (const float*)d_in[9];
  const float* bo = (const float*)d_in[10];
  const float* Wp = (const float*)d_in[11];
  const float* bp = (const float*)d_in[12];
  const float* Wa = (const float*)d_in[13];
  const float* ba = (const float*)d_in[14];
  const float* va = (const float*)d_in[15];
  unsigned short* wsb = (unsigned short*)d_ws;
  float* out = (float*)d_out;

  prep_weights<<<(PREP_TOTAL + 255) / 256, 256, 0, stream>>>(Wq, Wk, Wv, Wr, Wo, Wp, Wa,
                                                             wq_attn, br, bo, wsb);
  doc_encoder<<<4096, 512, 0, stream>>>(tokens, emb, wk_attn, bp, ba, va, wsb, out);
}

// Round 10
// 1128.444 us; speedup vs baseline: 1.1097x; 1.1097x over previous
//
#include <hip/hip_runtime.h>
#include <hip/hip_bf16.h>

typedef __attribute__((ext_vector_type(8))) short short8;
typedef __attribute__((ext_vector_type(4))) float f32x4;

// B=4096, S=64, V=50000, D=300, H=6, E=400, VS=200, DH=50
// ws layout (u16 elems): MFMA B-frag jobs, 512 elems per (tn,kt) tile:
// elem(lane,i) = W[k][n], n = tn*16+(lane&15), k = kt*32+(lane>>4)*8+i
#define KF 0             // 19 jobs Wk [19][10][512]; VF/CQF contiguous after
#define VF 97280         // 19 jobs Wv
#define CQF 194560       // 1 job: cols 0-5 = cq_h = Wq[:,blk]@wq_attn_h
#define WQ1 199680       // 19 jobs Wq (for T1 g-GEMM)
#define OFC 296960       // 19 jobs x 20kt [Wqo ; Wro]  (Wqo=Wq@Wo, Wro=Wr@Wo)
#define PFW 491520       // 25 jobs Wp
#define AFW 619520       // 13 jobs x 13kt Wa
#define BOBF 706048      // float[304]: bo + br@Wo
#define PREP_TOTAL 706656

#define MFMA(a, b, c) __builtin_amdgcn_mfma_f32_16x16x32_bf16((a), (b), (c), 0, 0, 0)

__device__ __forceinline__ unsigned short f2b(float f) {
  unsigned int u = __builtin_bit_cast(unsigned int, f);
  u += 0x7FFFu + ((u >> 16) & 1u);
  return (unsigned short)(u >> 16);
}
__device__ __forceinline__ float b2f(unsigned short h) {
  unsigned int u = ((unsigned int)h) << 16;
  return __builtin_bit_cast(float, u);
}

__global__ void prep_weights(const float* __restrict__ Wq, const float* __restrict__ Wk,
                             const float* __restrict__ Wv, const float* __restrict__ Wr,
                             const float* __restrict__ Wo, const float* __restrict__ Wp,
                             const float* __restrict__ Wa, const float* __restrict__ wq_attn,
                             const float* __restrict__ br, const float* __restrict__ bo,
                             unsigned short* __restrict__ ws) {
  int idx = blockIdx.x * blockDim.x + threadIdx.x;
  if (idx >= PREP_TOTAL) return;
  if (idx >= BOBF) {
    int n = idx - BOBF;
    if (n >= 304) return;
    float s = 0.f;
    if (n < 300) {
      s = bo[n];
      for (int m = 0; m < 300; ++m) s += br[m % 50] * Wo[m * 300 + n];
    }
    ((float*)(ws))[BOBF / 2 + n] = s;
    return;
  }
  float val = 0.f;
  if (idx < CQF) {                        // Wk / Wv plain
    int m = idx / 97280, local = idx % 97280;
    int tn = local / 5120, r = local % 5120;
    int kt = r / 512; r &= 511;
    int lane = r >> 3, i = r & 7;
    int n = tn * 16 + (lane & 15), k = kt * 32 + (lane >> 4) * 8 + i;
    if (n < 300 && k < 300) val = (m == 0) ? Wk[k * 300 + n] : Wv[k * 300 + n];
  } else if (idx < WQ1) {                 // cq job
    int local = idx - CQF;
    int kt = local / 512, r = local & 511;
    int lane = r >> 3, i = r & 7;
    int n = lane & 15, k = kt * 32 + (lane >> 4) * 8 + i;
    if (n < 6 && k < 300) {
      float s = 0.f;
      for (int d = 0; d < 50; ++d) s += Wq[k * 300 + 50 * n + d] * wq_attn[n * 50 + d];
      val = s;
    }
  } else if (idx < OFC) {                 // Wq plain (T1)
    int local = idx - WQ1;
    int tn = local / 5120, r = local % 5120;
    int kt = r / 512; r &= 511;
    int lane = r >> 3, i = r & 7;
    int n = tn * 16 + (lane & 15), k = kt * 32 + (lane >> 4) * 8 + i;
    if (n < 300 && k < 300) val = Wq[k * 300 + n];
  } else if (idx < PFW) {                 // [Wqo ; Wro] 20kt
    int local = idx - OFC;
    int tn = local / 10240, r = local % 10240;
    int kt = r / 512; r &= 511;
    int lane = r >> 3, i = r & 7;
    int n = tn * 16 + (lane & 15), kk = (lane >> 4) * 8 + i;
    if (n < 300) {
      if (kt < 10) {
        int k = kt * 32 + kk;
        if (k < 300) {                    // Wqo[k][n] = sum_j Wq[k][j] Wo[j][n]
          float s = 0.f;
          for (int j = 0; j < 300; ++j) s += Wq[k * 300 + j] * Wo[j * 300 + n];
          val = s;
        }
      } else {
        int k = (kt - 10) * 32 + kk;
        if (k < 300) {                    // Wro[k][n] = sum_j Wr[k%50][j] Wo[50*(k/50)+j][n]
          int h = k / 50, i2 = k % 50;
          float s = 0.f;
          for (int j = 0; j < 50; ++j) s += Wr[i2 * 50 + j] * Wo[(50 * h + j) * 300 + n];
          val = s;
        }
      }
    }
  } else if (idx < AFW) {                 // Wp
    int local = idx - PFW;
    int tn = local / 5120, r = local % 5120;
    int kt = r / 512; r &= 511;
    int lane = r >> 3, i = r & 7;
    int n = tn * 16 + (lane & 15), k = kt * 32 + (lane >> 4) * 8 + i;
    if (k < 300) val = Wp[k * 400 + n];
  } else {                                // Wa 13kt
    int local = idx - AFW;
    int tn = local / 6656, r = local % 6656;
    int kt = r / 512; r &= 511;
    int lane = r >> 3, i = r & 7;
    int n = tn * 16 + (lane & 15), k = kt * 32 + (lane >> 4) * 8 + i;
    if (n < 200 && k < 400) val = Wa[k * 200 + n];
  }
  ws[idx] = f2b(val);
}

// LDS layout (bytes), total 163712 <= 163840
#define MISCB 0       // float[1504]: aM[6][64] gB[304] gw[304] gkf[320] scp[128] wsm[64]
#define XBOFF 6016    // ushort [64][304] x ; later hb (h cols 0-303)
#define KBOFF 44928   // ushort [64][304] K ; later attn_out
#define VBOFF 83840   // ushort [64][304] v -> u ; later side (h cols 304-415) [64][112]
#define STGOFF 122752 // 2 x 20480 B staging buffers (buf stride 10240 elems)
#define SMEM_BYTES 163712
#define STR 304
#define SIDE_STR 112

typedef __attribute__((address_space(1))) void global_void;
typedef __attribute__((address_space(3))) void lds_void;

__device__ __forceinline__ void issue_seg(const unsigned short* g, unsigned short* l) {
  __builtin_amdgcn_global_load_lds((global_void*)g, (lds_void*)l, 16, 0, 0);
}

// Stage 2 jobs x nk tiles into dst [2][nk][512]; s1==nullptr -> second job invalid.
__device__ __forceinline__ void stage_pair(const unsigned short* s0, const unsigned short* s1,
                                           int nk, unsigned short* dst, int wv, int lane) {
  for (int s = wv; s < 2 * nk; s += 8) {
    int jj = (s >= nk);
    int kl = s - (jj ? nk : 0);
    const unsigned short* sp = jj ? s1 : s0;
    if (sp) issue_seg(sp + (size_t)kl * 512 + (size_t)lane * 8, dst + (size_t)s * 512);
  }
}

__global__ __launch_bounds__(512, 1) void doc_encoder(
    const int* __restrict__ tokens, const float* __restrict__ emb,
    const float* __restrict__ wk_attn, const float* __restrict__ bp_,
    const float* __restrict__ ba_, const float* __restrict__ va_,
    const unsigned short* __restrict__ ws, float* __restrict__ out) {
  __shared__ alignas(16) unsigned char smem[SMEM_BYTES];
  float* miscf = (float*)(smem + MISCB);
  unsigned short* xb = (unsigned short*)(smem + XBOFF);
  unsigned short* kb = (unsigned short*)(smem + KBOFF);
  unsigned short* vb = (unsigned short*)(smem + VBOFF);
  unsigned short* stg = (unsigned short*)(smem + STGOFF);
  unsigned short* Tm = stg;        // [16][304] overlay on buf0 (between B and attn)
  unsigned short* hb = xb;         // overlay after attn
  unsigned short* side = vb;       // overlay after attn
  float* gB = miscf + 384;   // [304]
  float* gw = miscf + 688;   // [304]
  float* gkf = miscf + 992;  // [320]
  float* scp = miscf + 1312; // [2][64]
  float* wsm = miscf + 1440; // [64]

  const int b = blockIdx.x;
  const int tid = threadIdx.x;
  const int lane = tid & 63;
  const int wv = tid >> 6;     // 0..7
  const int wm = wv & 3;       // M tile
  const int wn = wv >> 2;      // job select within chunk
  const int l15 = lane & 15;
  const int lg = lane >> 4;
  const int kofs = lg * 8;
  const int arow = wm * 16 + l15;
  const int cr0 = wm * 16 + lg * 4;
  const float* bobf = ((const float*)ws) + BOBF / 2;
  const float scale = 0.1414213562373095f;
  const f32x4 vzero = {0.f, 0.f, 0.f, 0.f};

  // issue phase-B chunk 0 (jobs 0,1) -> buf0; overlaps with gather below
  stage_pair(ws + KF, ws + KF + 5120, 10, stg, wv, lane);

  // ---- zero inits ----
  for (int i = tid; i < 64 * 4; i += 512) {
    int s = i >> 2, c = 300 + (i & 3);
    kb[s * STR + c] = 0; vb[s * STR + c] = 0;
  }
  if (tid < 20) gkf[300 + tid] = 0.f;
  if (tid < 16) kb[tid] = 0;                 // xb row63 kt9 over-read target

  // ---- gather x = emb[tokens[b]] -> xb bf16 [64][304] ----
  for (int i = tid; i < 64 * 38; i += 512) {
    int s = i / 38, c8 = (i % 38) * 8;
    int tok = tokens[b * 64 + s];
    const float* rp = emb + (size_t)tok * 300;
    short8 v;
    if (c8 + 8 <= 300) {
      f32x4 u0 = *(const f32x4*)(rp + c8);
      f32x4 u1 = *(const f32x4*)(rp + c8 + 4);
#pragma unroll
      for (int j = 0; j < 4; ++j) { v[j] = (short)f2b(u0[j]); v[4 + j] = (short)f2b(u1[j]); }
    } else {
#pragma unroll
      for (int j = 0; j < 8; ++j) v[j] = (c8 + j < 300) ? (short)f2b(rp[c8 + j]) : (short)0;
    }
    *(short8*)&xb[s * STR + c8] = v;
  }
  __syncthreads();   // B0

  short8 ax[10];
#pragma unroll
  for (int kt = 0; kt < 10; ++kt)
    ax[kt] = *(const short8*)&xb[arow * STR + kt * 32 + kofs];

  // ======== Phase B: K(19) V(19) cq(1) = 39 jobs, 20 chunks, DMA dbuf ========
  for (int ch = 0; ch < 20; ++ch) {
    __syncthreads();
    if (ch < 19) {
      int j0 = (ch + 1) * 2;
      const unsigned short* s0 = ws + KF + (size_t)j0 * 5120;
      stage_pair(s0, (j0 + 1 < 39) ? s0 + 5120 : nullptr, 10,
                 stg + ((ch + 1) & 1) * 10240, wv, lane);
    }
    int j = ch * 2 + wn;
    if (j < 39) {
      const unsigned short* bp = stg + (ch & 1) * 10240 + wn * 5120 + lane * 8;
      f32x4 a0 = vzero, a1 = vzero;
#pragma unroll
      for (int k = 0; k < 10; k += 2) {
        a0 = MFMA(ax[k], *(const short8*)(bp + k * 512), a0);
        a1 = MFMA(ax[k + 1], *(const short8*)(bp + (k + 1) * 512), a1);
      }
      f32x4 acc = a0 + a1;
      if (j < 19) {
        int n = j * 16 + l15;
        if (n < 300) {
#pragma unroll
          for (int r = 0; r < 4; ++r) kb[(cr0 + r) * STR + n] = f2b(acc[r]);
        }
      } else if (j < 38) {
        int n = (j - 19) * 16 + l15;
        if (n < 300) {
#pragma unroll
          for (int r = 0; r < 4; ++r) vb[(cr0 + r) * STR + n] = f2b(acc[r]);
        }
      } else if (l15 < 6) {
#pragma unroll
        for (int r = 0; r < 4; ++r) miscf[l15 * 64 + cr0 + r] = acc[r] * scale;
      }
    }
  }
  __syncthreads();

  // ---- alpha softmax (wave h) ----
  if (wv < 6) {
    float* aMh = miscf + wv * 64;
    float x = aMh[lane];
    float m = x;
#pragma unroll
    for (int off = 32; off; off >>= 1) m = fmaxf(m, __shfl_xor(m, off));
    float e = __expf(x - m);
    float ss = e;
#pragma unroll
    for (int off = 32; off; off >>= 1) ss += __shfl_xor(ss, off);
    aMh[lane] = e / ss;
  }
  __syncthreads();

  // ---- Tm zero (rows 6-15, tail, pads) + t_alpha rows 0-5 (buf0 free: last B read was buf1) ----
  for (int i = tid; i < 3056; i += 512) Tm[1824 + i] = 0;   // rows 6-15 + 16 tail
  if (tid < 24) { int rr = tid / 4, cc = 300 + (tid & 3); Tm[rr * STR + cc] = 0; }
  {
    int c = wv * 38 + lane;
    if (lane < 38 && c < 300) {
      float acc[6] = {0.f, 0.f, 0.f, 0.f, 0.f, 0.f};
      for (int s = 0; s < 64; ++s) {
        float xv = b2f(xb[s * STR + c]);
#pragma unroll
        for (int h = 0; h < 6; ++h) acc[h] += miscf[h * 64 + s] * xv;
      }
#pragma unroll
      for (int h = 0; h < 6; ++h) Tm[h * STR + c] = f2b(acc[h]);
    }
  }
  __syncthreads();

  // ---- T1: g = t_alpha @ Wq (19 jobs, direct L2 loads, one per wave round) ----
  {
    short8 aT[10];
#pragma unroll
    for (int kt = 0; kt < 10; ++kt)
      aT[kt] = *(const short8*)&Tm[l15 * STR + kt * 32 + kofs];
    for (int j = wv; j < 19; j += 8) {
      const unsigned short* bp = ws + WQ1 + (size_t)j * 5120 + lane * 8;
      f32x4 a0 = vzero, a1 = vzero;
#pragma unroll
      for (int k = 0; k < 10; k += 2) {
        a0 = MFMA(aT[k], *(const short8*)(bp + k * 512), a0);
        a1 = MFMA(aT[k + 1], *(const short8*)(bp + (k + 1) * 512), a1);
      }
      f32x4 acc = a0 + a1;
      int dt = j * 16 + l15;
#pragma unroll
      for (int r = 0; r < 4; ++r) {
        int h = lg * 4 + r;
        if (h < 6 && dt >= 50 * h && dt < 50 * h + 50) gB[dt] = acc[r];
      }
    }
  }
  __syncthreads();

  // issue attn chunk0 half0 -> buf0 (Tm dead); overlaps with stage C below
  stage_pair(ws + OFC, ws + OFC + 10240, 10, stg, wv, lane);

  if (tid < 300) gw[tid] = gB[tid] * wk_attn[tid];
  __syncthreads();

  // ---- beta softmax (wave h) ----
  if (wv < 6) {
    const int h = wv;
    float* aMh = miscf + h * 64;
    float p = 0.f;
    const unsigned short* krow = kb + lane * STR + 50 * h;
    for (int dd = 0; dd < 50; ++dd) p += gw[50 * h + dd] * b2f(krow[dd]);
    p *= scale;
    float m = p;
#pragma unroll
    for (int off = 32; off; off >>= 1) m = fmaxf(m, __shfl_xor(m, off));
    float e = __expf(p - m);
    float ss = e;
#pragma unroll
    for (int off = 32; off; off >>= 1) ss += __shfl_xor(ss, off);
    aMh[lane] = e / ss;
  }
  __syncthreads();
  // ---- gk = g o (beta^T k) ----
  if (wv < 6 && lane < 50) {
    const int h = wv;
    float gks = 0.f;
    const unsigned short* kcol = kb + 50 * h + lane;
    for (int s = 0; s < 64; ++s) gks += miscf[h * 64 + s] * b2f(kcol[s * STR]);
    gkf[50 * h + lane] = gB[50 * h + lane] * gks;
  }
  __syncthreads();

  // ---- u = gk o v in-place in vb ----
  for (int i = tid; i < 64 * 38; i += 512) {
    int s = i / 38, c8 = (i % 38) * 8;
    short8 vf = *(const short8*)&vb[s * STR + c8];
    short8 uf;
#pragma unroll
    for (int j = 0; j < 8; ++j) {
      int c = c8 + j;
      uf[j] = (c < 300) ? (short)f2b(gkf[c] * b2f((unsigned short)vf[j])) : (short)0;
    }
    *(short8*)&vb[s * STR + c8] = uf;
  }
  short8 ax2[10];
#pragma unroll
  for (int kt = 0; kt < 10; ++kt)
    ax2[kt] = *(const short8*)&xb[arow * STR + kt * 32 + kofs];

  // ======== attn_out = x@Wqo + u@Wro + bobf -> kb  (20 stages = 10 chunks x 2 halves) ========
  {
    f32x4 ac0 = vzero, ac1 = vzero;
    for (int t = 0; t < 20; ++t) {
      __syncthreads();
      if (t < 19) {
        int tn = t + 1, nc = tn >> 1, nh = tn & 1, j0 = nc * 2;
        const unsigned short* s0 = ws + OFC + (size_t)j0 * 10240 + (size_t)nh * 5120;
        stage_pair(s0, (j0 + 1 < 19) ? s0 + 10240 : nullptr, 10,
                   stg + (tn & 1) * 10240, wv, lane);
      }
      int half = t & 1, j = (t >> 1) * 2 + wn;
      if (j < 19) {
        const unsigned short* bp = stg + (t & 1) * 10240 + wn * 5120 + lane * 8;
        if (half == 0) {
          ac0 = vzero; ac1 = vzero;
#pragma unroll
          for (int k = 0; k < 10; k += 2) {
            ac0 = MFMA(ax2[k], *(const short8*)(bp + k * 512), ac0);
            ac1 = MFMA(ax2[k + 1], *(const short8*)(bp + (k + 1) * 512), ac1);
          }
        } else {
          const unsigned short* ub = vb + arow * STR + kofs;
#pragma unroll
          for (int k = 0; k < 10; k += 2) {
            ac0 = MFMA(*(const short8*)(ub + k * 32), *(const short8*)(bp + k * 512), ac0);
            ac1 = MFMA(*(const short8*)(ub + (k + 1) * 32), *(const short8*)(bp + (k + 1) * 512), ac1);
          }
          f32x4 acc = ac0 + ac1;
          int n = j * 16 + l15;
          if (n < 300) {
            float bias = bobf[n];
#pragma unroll
            for (int r = 0; r < 4; ++r) kb[(cr0 + r) * STR + n] = f2b(acc[r] + bias);
          }
        }
      }
    }
  }
  __syncthreads();

  // issue Wp chunk0 -> buf0; zero side pads (h cols 400-415 = side 96-111); load ao
  stage_pair(ws + PFW, ws + PFW + 5120, 10, stg, wv, lane);
  for (int i = tid; i < 64 * 16; i += 512) side[(i >> 4) * SIDE_STR + 96 + (i & 15)] = 0;
  short8 ao[10];
#pragma unroll
  for (int kt = 0; kt < 10; ++kt)
    ao[kt] = *(const short8*)&kb[arow * STR + kt * 32 + kofs];

  // ======== h = attn_out @ Wp + bp -> hb[304] + side[112]  (13 chunks) ========
  for (int ch = 0; ch < 13; ++ch) {
    __syncthreads();
    if (ch < 12) {
      int j0 = (ch + 1) * 2;
      const unsigned short* s0 = ws + PFW + (size_t)j0 * 5120;
      stage_pair(s0, (j0 + 1 < 25) ? s0 + 5120 : nullptr, 10,
                 stg + ((ch + 1) & 1) * 10240, wv, lane);
    }
    int j = ch * 2 + wn;
    if (j < 25) {
      const unsigned short* bp = stg + (ch & 1) * 10240 + wn * 5120 + lane * 8;
      f32x4 a0 = vzero, a1 = vzero;
#pragma unroll
      for (int k = 0; k < 10; k += 2) {
        a0 = MFMA(ao[k], *(const short8*)(bp + k * 512), a0);
        a1 = MFMA(ao[k + 1], *(const short8*)(bp + (k + 1) * 512), a1);
      }
      f32x4 acc = a0 + a1;
      int n = j * 16 + l15;   // < 400
      float bias = bp_[n];
#pragma unroll
      for (int r = 0; r < 4; ++r) {
        unsigned short val = f2b(acc[r] + bias);
        if (n < STR) hb[(cr0 + r) * STR + n] = val;
        else side[(cr0 + r) * SIDE_STR + (n - STR)] = val;
      }
    }
  }
  __syncthreads();

  // issue Wa t0 (chunk0 kt0-6) -> buf0; load ah
  stage_pair(ws + AFW, ws + AFW + 6656, 7, stg, wv, lane);
  short8 ah[13];
#pragma unroll
  for (int kt = 0; kt < 9; ++kt)
    ah[kt] = *(const short8*)&hb[arow * STR + kt * 32 + kofs];
  ah[9] = (lg < 2) ? *(const short8*)&hb[arow * STR + 288 + kofs]
                   : *(const short8*)&side[arow * SIDE_STR + (kofs - 16)];
  ah[10] = *(const short8*)&side[arow * SIDE_STR + 16 + kofs];
  ah[11] = *(const short8*)&side[arow * SIDE_STR + 48 + kofs];
  ah[12] = *(const short8*)&side[arow * SIDE_STR + 80 + kofs];

  // ======== scores = tanh(h@Wa + ba) @ va  (14 stages = 7 chunks x (7kt,6kt)) ========
  float sp[4] = {0.f, 0.f, 0.f, 0.f};
  {
    f32x4 wa0 = vzero, wa1 = vzero;
    for (int t = 0; t < 14; ++t) {
      __syncthreads();
      if (t < 13) {
        int tn = t + 1, nc = tn >> 1, nh = tn & 1, j0 = nc * 2;
        int k0 = nh ? 7 : 0, nk = nh ? 6 : 7;
        const unsigned short* s0 = ws + AFW + (size_t)j0 * 6656 + (size_t)k0 * 512;
        stage_pair(s0, (j0 + 1 < 13) ? s0 + 6656 : nullptr, nk,
                   stg + (tn & 1) * 10240, wv, lane);
      }
      int half = t & 1, j = (t >> 1) * 2 + wn;
      if (j < 13) {
        if (half == 0) {
          const unsigned short* bp = stg + (t & 1) * 10240 + wn * 3584 + lane * 8;
          wa0 = vzero; wa1 = vzero;
          wa0 = MFMA(ah[0], *(const short8*)(bp + 0 * 512), wa0);
          wa1 = MFMA(ah[1], *(const short8*)(bp + 1 * 512), wa1);
          wa0 = MFMA(ah[2], *(const short8*)(bp + 2 * 512), wa0);
          wa1 = MFMA(ah[3], *(const short8*)(bp + 3 * 512), wa1);
          wa0 = MFMA(ah[4], *(const short8*)(bp + 4 * 512), wa0);
          wa1 = MFMA(ah[5], *(const short8*)(bp + 5 * 512), wa1);
          wa0 = MFMA(ah[6], *(const short8*)(bp + 6 * 512), wa0);
        } else {
          const unsigned short* bp = stg + (t & 1) * 10240 + wn * 3072 + lane * 8;
          wa0 = MFMA(ah[7], *(const short8*)(bp + 0 * 512), wa0);
          wa1 = MFMA(ah[8], *(const short8*)(bp + 1 * 512), wa1);
          wa0 = MFMA(ah[9], *(const short8*)(bp + 2 * 512), wa0);
          wa1 = MFMA(ah[10], *(const short8*)(bp + 3 * 512), wa1);
          wa0 = MFMA(ah[11], *(const short8*)(bp + 4 * 512), wa0);
          wa1 = MFMA(ah[12], *(const short8*)(bp + 5 * 512), wa1);
          f32x4 acc = wa0 + wa1;
          int n = j * 16 + l15;
          if (n < 200) {
            float ban = ba_[n], van = va_[n];
#pragma unroll
            for (int r = 0; r < 4; ++r) {
              float x0 = fminf(fmaxf(acc[r] + ban, -15.f), 15.f);
              float t0 = __expf(2.f * x0);
              sp[r] += (t0 - 1.f) / (t0 + 1.f) * van;
            }
          }
        }
      }
    }
  }
#pragma unroll
  for (int off = 1; off < 16; off <<= 1) {
#pragma unroll
    for (int r = 0; r < 4; ++r) sp[r] += __shfl_xor(sp[r], off);
  }
  if (l15 == 0) {
#pragma unroll
    for (int r = 0; r < 4; ++r) scp[wn * 64 + cr0 + r] = sp[r];
  }
  __syncthreads();
  if (wv == 0) {
    float x = scp[lane] + scp[64 + lane];
    float m = x;
#pragma unroll
    for (int off = 32; off; off >>= 1) m = fmaxf(m, __shfl_xor(m, off));
    float e = __expf(x - m);
    float ss = e;
#pragma unroll
    for (int off = 32; off; off >>= 1) ss += __shfl_xor(ss, off);
    wsm[lane] = e / ss;
  }
  __syncthreads();

  // ---- pooled[e] = sum_s wsm[s] h[s][e] ----
  if (tid < 400) {
    float a0 = 0.f, a1 = 0.f, a2 = 0.f, a3 = 0.f;
    for (int s = 0; s < 64; s += 4) {
#pragma unroll
      for (int q = 0; q < 4; ++q) {
        int sq = s + q;
        float hv = (tid < STR) ? b2f(hb[sq * STR + tid])
                               : b2f(side[sq * SIDE_STR + tid - STR]);
        if (q == 0) a0 += wsm[sq] * hv;
        else if (q == 1) a1 += wsm[sq] * hv;
        else if (q == 2) a2 += wsm[sq] * hv;
        else a3 += wsm[sq] * hv;
      }
    }
    out[(size_t)b * 400 + tid] = (a0 + a1) + (a2 + a3);
  }
}

extern "C" void kernel_launch(void* const* d_in, const int* in_sizes, int n_in,
                              void* d_out, int out_size, void* d_ws, size_t ws_size,
                              hipStream_t stream) {
  (void)in_sizes; (void)n_in; (void)out_size; (void)ws_size;
  const int* tokens = (const int*)d_in[0];
  const float* emb = (const float*)d_in[1];
  const float* Wq = (const float*)d_in[2];
  const float* Wk = (const float*)d_in[3];
  const float* Wv = (const float*)d_in[4];
  const float* wq_attn = (const float*)d_in[5];
  const float* wk_attn = (const float*)d_in[6];
  const float* Wr = (const float*)d_in[7];
  const float* br = (const float*)d_in[8];
  const float* Wo = (const float*)d_in[9];
  const float* bo = (const float*)d_in[10];
  const float* Wp = (const float*)d_in[11];
  const float* bp = (const float*)d_in[12];
  const float* Wa = (const float*)d_in[13];
  const float* ba = (const float*)d_in[14];
  const float* va = (const float*)d_in[15];
  unsigned short* wsb = (unsigned short*)d_ws;
  float* out = (float*)d_out;

  prep_weights<<<(PREP_TOTAL + 255) / 256, 256, 0, stream>>>(Wq, Wk, Wv, Wr, Wo, Wp, Wa,
                                                             wq_attn, br, bo, wsb);
  doc_encoder<<<4096, 512, 0, stream>>>(tokens, emb, wk_attn, bp, ba, va, wsb, out);
}

// Round 11
// 1127.660 us; speedup vs baseline: 1.1105x; 1.0007x over previous
//
#include <hip/hip_runtime.h>
#include <hip/hip_bf16.h>

typedef __attribute__((ext_vector_type(8))) short short8;
typedef __attribute__((ext_vector_type(4))) float f32x4;

// B=4096, S=64, V=50000, D=300, H=6, E=400, VS=200, DH=50
// ws layout (u16 elems): MFMA B-frag jobs, 512 elems per (tn,kt) tile:
// elem(lane,i) = W[k][n], n = tn*16+(lane&15), k = kt*32+(lane>>4)*8+i
#define KF 0             // 19 jobs Wk [19][10][512]; VF/CQF contiguous after
#define VF 97280         // 19 jobs Wv
#define CQF 194560       // 1 job: cols 0-5 = cq_h = Wq[:,blk]@wq_attn_h
#define WQ1 199680       // 19 jobs Wq (for T1 g-GEMM)
#define OFC 296960       // 19 jobs x 20kt [Wqo ; Wro]  (Wqo=Wq@Wo, Wro=Wr@Wo)
#define PFW 491520       // 25 jobs Wp
#define AFW 619520       // 13 jobs x 13kt Wa
#define BOBF 706048      // float[304]: bo + br@Wo
#define PREP_TOTAL 706656

#define MFMA(a, b, c) __builtin_amdgcn_mfma_f32_16x16x32_bf16((a), (b), (c), 0, 0, 0)

__device__ __forceinline__ unsigned short f2b(float f) {
  unsigned int u = __builtin_bit_cast(unsigned int, f);
  u += 0x7FFFu + ((u >> 16) & 1u);
  return (unsigned short)(u >> 16);
}
__device__ __forceinline__ float b2f(unsigned short h) {
  unsigned int u = ((unsigned int)h) << 16;
  return __builtin_bit_cast(float, u);
}

__global__ void prep_weights(const float* __restrict__ Wq, const float* __restrict__ Wk,
                             const float* __restrict__ Wv, const float* __restrict__ Wr,
                             const float* __restrict__ Wo, const float* __restrict__ Wp,
                             const float* __restrict__ Wa, const float* __restrict__ wq_attn,
                             const float* __restrict__ br, const float* __restrict__ bo,
                             unsigned short* __restrict__ ws) {
  int idx = blockIdx.x * blockDim.x + threadIdx.x;
  if (idx >= PREP_TOTAL) return;
  if (idx >= BOBF) {
    int n = idx - BOBF;
    if (n >= 304) return;
    float s = 0.f;
    if (n < 300) {
      s = bo[n];
      for (int m = 0; m < 300; ++m) s += br[m % 50] * Wo[m * 300 + n];
    }
    ((float*)(ws))[BOBF / 2 + n] = s;
    return;
  }
  float val = 0.f;
  if (idx < CQF) {                        // Wk / Wv plain
    int m = idx / 97280, local = idx % 97280;
    int tn = local / 5120, r = local % 5120;
    int kt = r / 512; r &= 511;
    int lane = r >> 3, i = r & 7;
    int n = tn * 16 + (lane & 15), k = kt * 32 + (lane >> 4) * 8 + i;
    if (n < 300 && k < 300) val = (m == 0) ? Wk[k * 300 + n] : Wv[k * 300 + n];
  } else if (idx < WQ1) {                 // cq job
    int local = idx - CQF;
    int kt = local / 512, r = local & 511;
    int lane = r >> 3, i = r & 7;
    int n = lane & 15, k = kt * 32 + (lane >> 4) * 8 + i;
    if (n < 6 && k < 300) {
      float s = 0.f;
      for (int d = 0; d < 50; ++d) s += Wq[k * 300 + 50 * n + d] * wq_attn[n * 50 + d];
      val = s;
    }
  } else if (idx < OFC) {                 // Wq plain (T1)
    int local = idx - WQ1;
    int tn = local / 5120, r = local % 5120;
    int kt = r / 512; r &= 511;
    int lane = r >> 3, i = r & 7;
    int n = tn * 16 + (lane & 15), k = kt * 32 + (lane >> 4) * 8 + i;
    if (n < 300 && k < 300) val = Wq[k * 300 + n];
  } else if (idx < PFW) {                 // [Wqo ; Wro] 20kt
    int local = idx - OFC;
    int tn = local / 10240, r = local % 10240;
    int kt = r / 512; r &= 511;
    int lane = r >> 3, i = r & 7;
    int n = tn * 16 + (lane & 15), kk = (lane >> 4) * 8 + i;
    if (n < 300) {
      if (kt < 10) {
        int k = kt * 32 + kk;
        if (k < 300) {                    // Wqo[k][n] = sum_j Wq[k][j] Wo[j][n]
          float s = 0.f;
          for (int j = 0; j < 300; ++j) s += Wq[k * 300 + j] * Wo[j * 300 + n];
          val = s;
        }
      } else {
        int k = (kt - 10) * 32 + kk;
        if (k < 300) {                    // Wro[k][n] = sum_j Wr[k%50][j] Wo[50*(k/50)+j][n]
          int h = k / 50, i2 = k % 50;
          float s = 0.f;
          for (int j = 0; j < 50; ++j) s += Wr[i2 * 50 + j] * Wo[(50 * h + j) * 300 + n];
          val = s;
        }
      }
    }
  } else if (idx < AFW) {                 // Wp
    int local = idx - PFW;
    int tn = local / 5120, r = local % 5120;
    int kt = r / 512; r &= 511;
    int lane = r >> 3, i = r & 7;
    int n = tn * 16 + (lane & 15), k = kt * 32 + (lane >> 4) * 8 + i;
    if (k < 300) val = Wp[k * 400 + n];
  } else {                                // Wa 13kt
    int local = idx - AFW;
    int tn = local / 6656, r = local % 6656;
    int kt = r / 512; r &= 511;
    int lane = r >> 3, i = r & 7;
    int n = tn * 16 + (lane & 15), k = kt * 32 + (lane >> 4) * 8 + i;
    if (n < 200 && k < 400) val = Wa[k * 200 + n];
  }
  ws[idx] = f2b(val);
}

// LDS layout (bytes), total 163712 <= 163840
#define MISCB 0       // float[1504]: aM[6][64] gB[304] gw[304] gkf[320] scp[128] wsm[64]
#define XBOFF 6016    // ushort [64][304] x ; later hb (h cols 0-303)
#define KBOFF 44928   // ushort [64][304] K ; later attn_out
#define VBOFF 83840   // ushort [64][304] v -> u ; later side (h cols 304-415) [64][112]
#define STGOFF 122752 // 2 x 20480 B staging buffers (buf stride 10240 elems)
#define SMEM_BYTES 163712
#define STR 304
#define SIDE_STR 112

typedef __attribute__((address_space(1))) void global_void;
typedef __attribute__((address_space(3))) void lds_void;

__device__ __forceinline__ void issue_seg(const unsigned short* g, unsigned short* l) {
  __builtin_amdgcn_global_load_lds((global_void*)g, (lds_void*)l, 16, 0, 0);
}

// Stage 2 jobs x nk tiles into dst [2][nk][512]; s1==nullptr -> second job invalid.
__device__ __forceinline__ void stage_pair(const unsigned short* s0, const unsigned short* s1,
                                           int nk, unsigned short* dst, int wv, int lane) {
  for (int s = wv; s < 2 * nk; s += 8) {
    int jj = (s >= nk);
    int kl = s - (jj ? nk : 0);
    const unsigned short* sp = jj ? s1 : s0;
    if (sp) issue_seg(sp + (size_t)kl * 512 + (size_t)lane * 8, dst + (size_t)s * 512);
  }
}

__global__ __launch_bounds__(512, 1) void doc_encoder(
    const int* __restrict__ tokens, const float* __restrict__ emb,
    const float* __restrict__ wk_attn, const float* __restrict__ bp_,
    const float* __restrict__ ba_, const float* __restrict__ va_,
    const unsigned short* __restrict__ ws, float* __restrict__ out) {
  __shared__ alignas(16) unsigned char smem[SMEM_BYTES];
  float* miscf = (float*)(smem + MISCB);
  unsigned short* xb = (unsigned short*)(smem + XBOFF);
  unsigned short* kb = (unsigned short*)(smem + KBOFF);
  unsigned short* vb = (unsigned short*)(smem + VBOFF);
  unsigned short* stg = (unsigned short*)(smem + STGOFF);
  unsigned short* Tm = stg;        // [16][304] overlay on buf0 (between B and attn)
  unsigned short* hb = xb;         // overlay after attn
  unsigned short* side = vb;       // overlay after attn
  float* gB = miscf + 384;   // [304]
  float* gw = miscf + 688;   // [304]
  float* gkf = miscf + 992;  // [320]
  float* scp = miscf + 1312; // [2][64]
  float* wsm = miscf + 1440; // [64]

  const int b = blockIdx.x;
  const int tid = threadIdx.x;
  const int lane = tid & 63;
  const int wv = tid >> 6;     // 0..7
  const int wm = wv & 3;       // M tile
  const int wn = wv >> 2;      // job select within chunk
  const int l15 = lane & 15;
  const int lg = lane >> 4;
  const int kofs = lg * 8;
  const int arow = wm * 16 + l15;
  const int cr0 = wm * 16 + lg * 4;
  const float* bobf = ((const float*)ws) + BOBF / 2;
  const float scale = 0.1414213562373095f;
  const f32x4 vzero = {0.f, 0.f, 0.f, 0.f};

  // issue phase-B chunk 0 (jobs 0,1) -> buf0; overlaps with gather below
  stage_pair(ws + KF, ws + KF + 5120, 10, stg, wv, lane);

  // ---- zero inits ----
  for (int i = tid; i < 64 * 4; i += 512) {
    int s = i >> 2, c = 300 + (i & 3);
    kb[s * STR + c] = 0; vb[s * STR + c] = 0;
  }
  if (tid < 20) gkf[300 + tid] = 0.f;
  if (tid < 16) kb[tid] = 0;                 // xb row63 kt9 over-read target

  // ---- gather x = emb[tokens[b]] -> xb bf16 [64][304] ----
  for (int i = tid; i < 64 * 38; i += 512) {
    int s = i / 38, c8 = (i % 38) * 8;
    int tok = tokens[b * 64 + s];
    const float* rp = emb + (size_t)tok * 300;
    short8 v;
    if (c8 + 8 <= 300) {
      f32x4 u0 = *(const f32x4*)(rp + c8);
      f32x4 u1 = *(const f32x4*)(rp + c8 + 4);
#pragma unroll
      for (int j = 0; j < 4; ++j) { v[j] = (short)f2b(u0[j]); v[4 + j] = (short)f2b(u1[j]); }
    } else {
#pragma unroll
      for (int j = 0; j < 8; ++j) v[j] = (c8 + j < 300) ? (short)f2b(rp[c8 + j]) : (short)0;
    }
    *(short8*)&xb[s * STR + c8] = v;
  }
  __syncthreads();   // B0

  short8 ax[10];
#pragma unroll
  for (int kt = 0; kt < 10; ++kt)
    ax[kt] = *(const short8*)&xb[arow * STR + kt * 32 + kofs];

  // ======== Phase B: K(19) V(19) cq(1) = 39 jobs, 20 chunks, DMA dbuf ========
  for (int ch = 0; ch < 20; ++ch) {
    __syncthreads();
    if (ch < 19) {
      int j0 = (ch + 1) * 2;
      const unsigned short* s0 = ws + KF + (size_t)j0 * 5120;
      stage_pair(s0, (j0 + 1 < 39) ? s0 + 5120 : nullptr, 10,
                 stg + ((ch + 1) & 1) * 10240, wv, lane);
    }
    int j = ch * 2 + wn;
    if (j < 39) {
      const unsigned short* bp = stg + (ch & 1) * 10240 + wn * 5120 + lane * 8;
      f32x4 a0 = vzero, a1 = vzero;
#pragma unroll
      for (int k = 0; k < 10; k += 2) {
        a0 = MFMA(ax[k], *(const short8*)(bp + k * 512), a0);
        a1 = MFMA(ax[k + 1], *(const short8*)(bp + (k + 1) * 512), a1);
      }
      f32x4 acc = a0 + a1;
      if (j < 19) {
        int n = j * 16 + l15;
        if (n < 300) {
#pragma unroll
          for (int r = 0; r < 4; ++r) kb[(cr0 + r) * STR + n] = f2b(acc[r]);
        }
      } else if (j < 38) {
        int n = (j - 19) * 16 + l15;
        if (n < 300) {
#pragma unroll
          for (int r = 0; r < 4; ++r) vb[(cr0 + r) * STR + n] = f2b(acc[r]);
        }
      } else if (l15 < 6) {
#pragma unroll
        for (int r = 0; r < 4; ++r) miscf[l15 * 64 + cr0 + r] = acc[r] * scale;
      }
    }
  }
  __syncthreads();

  // ---- alpha softmax (wave h) ----
  if (wv < 6) {
    float* aMh = miscf + wv * 64;
    float x = aMh[lane];
    float m = x;
#pragma unroll
    for (int off = 32; off; off >>= 1) m = fmaxf(m, __shfl_xor(m, off));
    float e = __expf(x - m);
    float ss = e;
#pragma unroll
    for (int off = 32; off; off >>= 1) ss += __shfl_xor(ss, off);
    aMh[lane] = e / ss;
  }
  __syncthreads();

  // ---- Tm zero (rows 6-15, tail, pads) + t_alpha rows 0-5 (buf0 free: last B read was buf1) ----
  for (int i = tid; i < 3056; i += 512) Tm[1824 + i] = 0;   // rows 6-15 + 16 tail
  if (tid < 24) { int rr = tid / 4, cc = 300 + (tid & 3); Tm[rr * STR + cc] = 0; }
  {
    int c = wv * 38 + lane;
    if (lane < 38 && c < 300) {
      float acc[6] = {0.f, 0.f, 0.f, 0.f, 0.f, 0.f};
      for (int s = 0; s < 64; ++s) {
        float xv = b2f(xb[s * STR + c]);
#pragma unroll
        for (int h = 0; h < 6; ++h) acc[h] += miscf[h * 64 + s] * xv;
      }
#pragma unroll
      for (int h = 0; h < 6; ++h) Tm[h * STR + c] = f2b(acc[h]);
    }
  }
  __syncthreads();

  // ---- T1: g = t_alpha @ Wq (19 jobs, direct L2 loads, one per wave round) ----
  {
    short8 aT[10];
#pragma unroll
    for (int kt = 0; kt < 10; ++kt)
      aT[kt] = *(const short8*)&Tm[l15 * STR + kt * 32 + kofs];
    for (int j = wv; j < 19; j += 8) {
      const unsigned short* bp = ws + WQ1 + (size_t)j * 5120 + lane * 8;
      f32x4 a0 = vzero, a1 = vzero;
#pragma unroll
      for (int k = 0; k < 10; k += 2) {
        a0 = MFMA(aT[k], *(const short8*)(bp + k * 512), a0);
        a1 = MFMA(aT[k + 1], *(const short8*)(bp + (k + 1) * 512), a1);
      }
      f32x4 acc = a0 + a1;
      int dt = j * 16 + l15;
#pragma unroll
      for (int r = 0; r < 4; ++r) {
        int h = lg * 4 + r;
        if (h < 6 && dt >= 50 * h && dt < 50 * h + 50) gB[dt] = acc[r];
      }
    }
  }
  __syncthreads();

  // issue attn chunk0 half0 -> buf0 (Tm dead); overlaps with stage C below
  stage_pair(ws + OFC, ws + OFC + 10240, 10, stg, wv, lane);

  if (tid < 300) gw[tid] = gB[tid] * wk_attn[tid];
  __syncthreads();

  // ---- beta softmax (wave h) ----
  if (wv < 6) {
    const int h = wv;
    float* aMh = miscf + h * 64;
    float p = 0.f;
    const unsigned short* krow = kb + lane * STR + 50 * h;
    for (int dd = 0; dd < 50; ++dd) p += gw[50 * h + dd] * b2f(krow[dd]);
    p *= scale;
    float m = p;
#pragma unroll
    for (int off = 32; off; off >>= 1) m = fmaxf(m, __shfl_xor(m, off));
    float e = __expf(p - m);
    float ss = e;
#pragma unroll
    for (int off = 32; off; off >>= 1) ss += __shfl_xor(ss, off);
    aMh[lane] = e / ss;
  }
  __syncthreads();
  // ---- gk = g o (beta^T k) ----
  if (wv < 6 && lane < 50) {
    const int h = wv;
    float gks = 0.f;
    const unsigned short* kcol = kb + 50 * h + lane;
    for (int s = 0; s < 64; ++s) gks += miscf[h * 64 + s] * b2f(kcol[s * STR]);
    gkf[50 * h + lane] = gB[50 * h + lane] * gks;
  }
  __syncthreads();

  // ---- u = gk o v in-place in vb ----
  for (int i = tid; i < 64 * 38; i += 512) {
    int s = i / 38, c8 = (i % 38) * 8;
    short8 vf = *(const short8*)&vb[s * STR + c8];
    short8 uf;
#pragma unroll
    for (int j = 0; j < 8; ++j) {
      int c = c8 + j;
      uf[j] = (c < 300) ? (short)f2b(gkf[c] * b2f((unsigned short)vf[j])) : (short)0;
    }
    *(short8*)&vb[s * STR + c8] = uf;
  }
  short8 ax2[10];
#pragma unroll
  for (int kt = 0; kt < 10; ++kt)
    ax2[kt] = *(const short8*)&xb[arow * STR + kt * 32 + kofs];

  // ======== attn_out = x@Wqo + u@Wro + bobf -> kb  (20 stages = 10 chunks x 2 halves) ========
  {
    f32x4 ac0 = vzero, ac1 = vzero;
    for (int t = 0; t < 20; ++t) {
      __syncthreads();
      if (t < 19) {
        int tn = t + 1, nc = tn >> 1, nh = tn & 1, j0 = nc * 2;
        const unsigned short* s0 = ws + OFC + (size_t)j0 * 10240 + (size_t)nh * 5120;
        stage_pair(s0, (j0 + 1 < 19) ? s0 + 10240 : nullptr, 10,
                   stg + (tn & 1) * 10240, wv, lane);
      }
      int half = t & 1, j = (t >> 1) * 2 + wn;
      if (j < 19) {
        const unsigned short* bp = stg + (t & 1) * 10240 + wn * 5120 + lane * 8;
        if (half == 0) {
          ac0 = vzero; ac1 = vzero;
#pragma unroll
          for (int k = 0; k < 10; k += 2) {
            ac0 = MFMA(ax2[k], *(const short8*)(bp + k * 512), ac0);
            ac1 = MFMA(ax2[k + 1], *(const short8*)(bp + (k + 1) * 512), ac1);
          }
        } else {
          const unsigned short* ub = vb + arow * STR + kofs;
#pragma unroll
          for (int k = 0; k < 10; k += 2) {
            ac0 = MFMA(*(const short8*)(ub + k * 32), *(const short8*)(bp + k * 512), ac0);
            ac1 = MFMA(*(const short8*)(ub + (k + 1) * 32), *(const short8*)(bp + (k + 1) * 512), ac1);
          }
          f32x4 acc = ac0 + ac1;
          int n = j * 16 + l15;
          if (n < 300) {
            float bias = bobf[n];
#pragma unroll
            for (int r = 0; r < 4; ++r) kb[(cr0 + r) * STR + n] = f2b(acc[r] + bias);
          }
        }
      }
    }
  }
  __syncthreads();

  // issue Wp chunk0 -> buf0; zero side pads (h cols 400-415 = side 96-111); load ao
  stage_pair(ws + PFW, ws + PFW + 5120, 10, stg, wv, lane);
  for (int i = tid; i < 64 * 16; i += 512) side[(i >> 4) * SIDE_STR + 96 + (i & 15)] = 0;
  short8 ao[10];
#pragma unroll
  for (int kt = 0; kt < 10; ++kt)
    ao[kt] = *(const short8*)&kb[arow * STR + kt * 32 + kofs];

  // ======== h = attn_out @ Wp + bp -> hb[304] + side[112]  (13 chunks) ========
  for (int ch = 0; ch < 13; ++ch) {
    __syncthreads();
    if (ch < 12) {
      int j0 = (ch + 1) * 2;
      const unsigned short* s0 = ws + PFW + (size_t)j0 * 5120;
      stage_pair(s0, (j0 + 1 < 25) ? s0 + 5120 : nullptr, 10,
                 stg + ((ch + 1) & 1) * 10240, wv, lane);
    }
    int j = ch * 2 + wn;
    if (j < 25) {
      const unsigned short* bp = stg + (ch & 1) * 10240 + wn * 5120 + lane * 8;
      f32x4 a0 = vzero, a1 = vzero;
#pragma unroll
      for (int k = 0; k < 10; k += 2) {
        a0 = MFMA(ao[k], *(const short8*)(bp + k * 512), a0);
        a1 = MFMA(ao[k + 1], *(const short8*)(bp + (k + 1) * 512), a1);
      }
      f32x4 acc = a0 + a1;
      int n = j * 16 + l15;   // < 400
      float bias = bp_[n];
#pragma unroll
      for (int r = 0; r < 4; ++r) {
        unsigned short val = f2b(acc[r] + bias);
        if (n < STR) hb[(cr0 + r) * STR + n] = val;
        else side[(cr0 + r) * SIDE_STR + (n - STR)] = val;
      }
    }
  }
  __syncthreads();

  // issue Wa t0 (chunk0 kt0-6) -> buf0; load ah
  stage_pair(ws + AFW, ws + AFW + 6656, 7, stg, wv, lane);
  short8 ah[13];
#pragma unroll
  for (int kt = 0; kt < 9; ++kt)
    ah[kt] = *(const short8*)&hb[arow * STR + kt * 32 + kofs];
  ah[9] = (lg < 2) ? *(const short8*)&hb[arow * STR + 288 + kofs]
                   : *(const short8*)&side[arow * SIDE_STR + (kofs - 16)];
  ah[10] = *(const short8*)&side[arow * SIDE_STR + 16 + kofs];
  ah[11] = *(const short8*)&side[arow * SIDE_STR + 48 + kofs];
  ah[12] = *(const short8*)&side[arow * SIDE_STR + 80 + kofs];

  // ======== scores = tanh(h@Wa + ba) @ va  (14 stages = 7 chunks x (7kt,6kt)) ========
  float sp[4] = {0.f, 0.f, 0.f, 0.f};
  {
    f32x4 wa0 = vzero, wa1 = vzero;
    for (int t = 0; t < 14; ++t) {
      __syncthreads();
      if (t < 13) {
        int tn = t + 1, nc = tn >> 1, nh = tn & 1, j0 = nc * 2;
        int k0 = nh ? 7 : 0, nk = nh ? 6 : 7;
        const unsigned short* s0 = ws + AFW + (size_t)j0 * 6656 + (size_t)k0 * 512;
        stage_pair(s0, (j0 + 1 < 13) ? s0 + 6656 : nullptr, nk,
                   stg + (tn & 1) * 10240, wv, lane);
      }
      int half = t & 1, j = (t >> 1) * 2 + wn;
      if (j < 13) {
        if (half == 0) {
          const unsigned short* bp = stg + (t & 1) * 10240 + wn * 3584 + lane * 8;
          wa0 = vzero; wa1 = vzero;
          wa0 = MFMA(ah[0], *(const short8*)(bp + 0 * 512), wa0);
          wa1 = MFMA(ah[1], *(const short8*)(bp + 1 * 512), wa1);
          wa0 = MFMA(ah[2], *(const short8*)(bp + 2 * 512), wa0);
          wa1 = MFMA(ah[3], *(const short8*)(bp + 3 * 512), wa1);
          wa0 = MFMA(ah[4], *(const short8*)(bp + 4 * 512), wa0);
          wa1 = MFMA(ah[5], *(const short8*)(bp + 5 * 512), wa1);
          wa0 = MFMA(ah[6], *(const short8*)(bp + 6 * 512), wa0);
        } else {
          const unsigned short* bp = stg + (t & 1) * 10240 + wn * 3072 + lane * 8;
          wa0 = MFMA(ah[7], *(const short8*)(bp + 0 * 512), wa0);
          wa1 = MFMA(ah[8], *(const short8*)(bp + 1 * 512), wa1);
          wa0 = MFMA(ah[9], *(const short8*)(bp + 2 * 512), wa0);
          wa1 = MFMA(ah[10], *(const short8*)(bp + 3 * 512), wa1);
          wa0 = MFMA(ah[11], *(const short8*)(bp + 4 * 512), wa0);
          wa1 = MFMA(ah[12], *(const short8*)(bp + 5 * 512), wa1);
          f32x4 acc = wa0 + wa1;
          int n = j * 16 + l15;
          if (n < 200) {
            float ban = ba_[n], van = va_[n];
#pragma unroll
            for (int r = 0; r < 4; ++r) {
              float x0 = fminf(fmaxf(acc[r] + ban, -15.f), 15.f);
              float t0 = __expf(2.f * x0);
              sp[r] += (t0 - 1.f) / (t0 + 1.f) * van;
            }
          }
        }
      }
    }
  }
#pragma unroll
  for (int off = 1; off < 16; off <<= 1) {
#pragma unroll
    for (int r = 0; r < 4; ++r) sp[r] += __shfl_xor(sp[r], off);
  }
  if (l15 == 0) {
#pragma unroll
    for (int r = 0; r < 4; ++r) scp[wn * 64 + cr0 + r] = sp[r];
  }
  __syncthreads();
  if (wv == 0) {
    float x = scp[lane] + scp[64 + lane];
    float m = x;
#pragma unroll
    for (int off = 32; off; off >>= 1) m = fmaxf(m, __shfl_xor(m, off));
    float e = __expf(x - m);
    float ss = e;
#pragma unroll
    for (int off = 32; off; off >>= 1) ss += __shfl_xor(ss, off);
    wsm[lane] = e / ss;
  }
  __syncthreads();

  // ---- pooled[e] = sum_s wsm[s] h[s][e] ----
  if (tid < 400) {
    float a0 = 0.f, a1 = 0.f, a2 = 0.f, a3 = 0.f;
    for (int s = 0; s < 64; s += 4) {
#pragma unroll
      for (int q = 0; q < 4; ++q) {
        int sq = s + q;
        float hv = (tid < STR) ? b2f(hb[sq * STR + tid])
                               : b2f(side[sq * SIDE_STR + tid - STR]);
        if (q == 0) a0 += wsm[sq] * hv;
        else if (q == 1) a1 += wsm[sq] * hv;
        else if (q == 2) a2 += wsm[sq] * hv;
        else a3 += wsm[sq] * hv;
      }
    }
    out[(size_t)b * 400 + tid] = (a0 + a1) + (a2 + a3);
  }
}

extern "C" void kernel_launch(void* const* d_in, const int* in_sizes, int n_in,
                              void* d_out, int out_size, void* d_ws, size_t ws_size,
                              hipStream_t stream) {
  (void)in_sizes; (void)n_in; (void)out_size; (void)ws_size;
  const int* tokens = (const int*)d_in[0];
  const float* emb = (const float*)d_in[1];
  const float* Wq = (const float*)d_in[2];
  const float* Wk = (const float*)d_in[3];
  const float* Wv = (const float*)d_in[4];
  const float* wq_attn = (const float*)d_in[5];
  const float* wk_attn = (const float*)d_in[6];
  const float* Wr = (const float*)d_in[7];
  const float* br = (const float*)d_in[8];
  const float* Wo = (const float*)d_in[9];
  const float* bo = (const float*)d_in[10];
  const float* Wp = (const float*)d_in[11];
  const float* bp = (const float*)d_in[12];
  const float* Wa = (const float*)d_in[13];
  const float* ba = (const float*)d_in[14];
  const float* va = (const float*)d_in[15];
  unsigned short* wsb = (unsigned short*)d_ws;
  float* out = (float*)d_out;

  prep_weights<<<(PREP_TOTAL + 255) / 256, 256, 0, stream>>>(Wq, Wk, Wv, Wr, Wo, Wp, Wa,
                                                             wq_attn, br, bo, wsb);
  doc_encoder<<<4096, 512, 0, stream>>>(tokens, emb, wk_attn, bp, ba, va, wsb, out);
}

// Round 12
// 1122.174 us; speedup vs baseline: 1.1159x; 1.0049x over previous
//
#include <hip/hip_runtime.h>
#include <hip/hip_bf16.h>

typedef __attribute__((ext_vector_type(8))) short short8;
typedef __attribute__((ext_vector_type(4))) float f32x4;

// B=4096, S=64, V=50000, D=300, H=6, E=400, VS=200, DH=50
// ws layout (u16 elems): MFMA B-frag jobs, 512 elems per (tn,kt) tile:
// elem(lane,i) = W[k][n], n = tn*16+(lane&15), k = kt*32+(lane>>4)*8+i
#define KF 0             // 19 jobs Wk [19][10][512]; VF/CQF contiguous after
#define VF 97280         // 19 jobs Wv
#define CQF 194560       // 1 job: cols 0-5 = cq_h = Wq[:,blk]@wq_attn_h
#define WQ1 199680       // 19 jobs Wq (for T1 g-GEMM)
#define OFC 296960       // 19 jobs x 20kt [Wqo ; Wro]  (Wqo=Wq@Wo, Wro=Wr@Wo)
#define PFW 491520       // 25 jobs Wp
#define AFW 619520       // 13 jobs x 13kt Wa
#define BOBF 706048      // float[304]: bo + br@Wo
#define PREP_TOTAL 706656

#define MFMA(a, b, c) __builtin_amdgcn_mfma_f32_16x16x32_bf16((a), (b), (c), 0, 0, 0)

__device__ __forceinline__ unsigned short f2b(float f) {
  unsigned int u = __builtin_bit_cast(unsigned int, f);
  u += 0x7FFFu + ((u >> 16) & 1u);
  return (unsigned short)(u >> 16);
}
__device__ __forceinline__ float b2f(unsigned short h) {
  unsigned int u = ((unsigned int)h) << 16;
  return __builtin_bit_cast(float, u);
}

__global__ void prep_weights(const float* __restrict__ Wq, const float* __restrict__ Wk,
                             const float* __restrict__ Wv, const float* __restrict__ Wr,
                             const float* __restrict__ Wo, const float* __restrict__ Wp,
                             const float* __restrict__ Wa, const float* __restrict__ wq_attn,
                             const float* __restrict__ br, const float* __restrict__ bo,
                             unsigned short* __restrict__ ws) {
  int idx = blockIdx.x * blockDim.x + threadIdx.x;
  if (idx >= PREP_TOTAL) return;
  if (idx >= BOBF) {
    int n = idx - BOBF;
    if (n >= 304) return;
    float s = 0.f;
    if (n < 300) {
      s = bo[n];
      for (int m = 0; m < 300; ++m) s += br[m % 50] * Wo[m * 300 + n];
    }
    ((float*)(ws))[BOBF / 2 + n] = s;
    return;
  }
  float val = 0.f;
  if (idx < CQF) {                        // Wk / Wv plain
    int m = idx / 97280, local = idx % 97280;
    int tn = local / 5120, r = local % 5120;
    int kt = r / 512; r &= 511;
    int lane = r >> 3, i = r & 7;
    int n = tn * 16 + (lane & 15), k = kt * 32 + (lane >> 4) * 8 + i;
    if (n < 300 && k < 300) val = (m == 0) ? Wk[k * 300 + n] : Wv[k * 300 + n];
  } else if (idx < WQ1) {                 // cq job
    int local = idx - CQF;
    int kt = local / 512, r = local & 511;
    int lane = r >> 3, i = r & 7;
    int n = lane & 15, k = kt * 32 + (lane >> 4) * 8 + i;
    if (n < 6 && k < 300) {
      float s = 0.f;
      for (int d = 0; d < 50; ++d) s += Wq[k * 300 + 50 * n + d] * wq_attn[n * 50 + d];
      val = s;
    }
  } else if (idx < OFC) {                 // Wq plain (T1)
    int local = idx - WQ1;
    int tn = local / 5120, r = local % 5120;
    int kt = r / 512; r &= 511;
    int lane = r >> 3, i = r & 7;
    int n = tn * 16 + (lane & 15), k = kt * 32 + (lane >> 4) * 8 + i;
    if (n < 300 && k < 300) val = Wq[k * 300 + n];
  } else if (idx < PFW) {                 // [Wqo ; Wro] 20kt
    int local = idx - OFC;
    int tn = local / 10240, r = local % 10240;
    int kt = r / 512; r &= 511;
    int lane = r >> 3, i = r & 7;
    int n = tn * 16 + (lane & 15), kk = (lane >> 4) * 8 + i;
    if (n < 300) {
      if (kt < 10) {
        int k = kt * 32 + kk;
        if (k < 300) {                    // Wqo[k][n] = sum_j Wq[k][j] Wo[j][n]
          float s = 0.f;
          for (int j = 0; j < 300; ++j) s += Wq[k * 300 + j] * Wo[j * 300 + n];
          val = s;
        }
      } else {
        int k = (kt - 10) * 32 + kk;
        if (k < 300) {                    // Wro[k][n] = sum_j Wr[k%50][j] Wo[50*(k/50)+j][n]
          int h = k / 50, i2 = k % 50;
          float s = 0.f;
          for (int j = 0; j < 50; ++j) s += Wr[i2 * 50 + j] * Wo[(50 * h + j) * 300 + n];
          val = s;
        }
      }
    }
  } else if (idx < AFW) {                 // Wp
    int local = idx - PFW;
    int tn = local / 5120, r = local % 5120;
    int kt = r / 512; r &= 511;
    int lane = r >> 3, i = r & 7;
    int n = tn * 16 + (lane & 15), k = kt * 32 + (lane >> 4) * 8 + i;
    if (k < 300) val = Wp[k * 400 + n];
  } else {                                // Wa 13kt
    int local = idx - AFW;
    int tn = local / 6656, r = local % 6656;
    int kt = r / 512; r &= 511;
    int lane = r >> 3, i = r & 7;
    int n = tn * 16 + (lane & 15), k = kt * 32 + (lane >> 4) * 8 + i;
    if (n < 200 && k < 400) val = Wa[k * 200 + n];
  }
  ws[idx] = f2b(val);
}

// LDS layout (bytes), total 163712 <= 163840
#define MISCB 0       // float[1504]: aM[6][64] gB[304] gw[304] gkf[320] scp[128] wsm[64]
#define XBOFF 6016    // ushort [64][304] x ; later hb (h cols 0-303)
#define KBOFF 44928   // ushort [64][304] K ; later attn_out
#define VBOFF 83840   // ushort [64][304] v -> u ; later side (h cols 304-415) [64][112]
#define STGOFF 122752 // 2 x 20480 B staging buffers (buf stride 10240 elems)
#define SMEM_BYTES 163712
#define STR 304
#define SIDE_STR 112

typedef __attribute__((address_space(1))) void global_void;
typedef __attribute__((address_space(3))) void lds_void;

__device__ __forceinline__ void issue_seg(const unsigned short* g, unsigned short* l) {
  __builtin_amdgcn_global_load_lds((global_void*)g, (lds_void*)l, 16, 0, 0);
}

// Stage 2 jobs x nk tiles into dst [2][nk][512]; s1==nullptr -> second job invalid.
__device__ __forceinline__ void stage_pair(const unsigned short* s0, const unsigned short* s1,
                                           int nk, unsigned short* dst, int wv, int lane) {
  for (int s = wv; s < 2 * nk; s += 8) {
    int jj = (s >= nk);
    int kl = s - (jj ? nk : 0);
    const unsigned short* sp = jj ? s1 : s0;
    if (sp) issue_seg(sp + (size_t)kl * 512 + (size_t)lane * 8, dst + (size_t)s * 512);
  }
}

__global__ __launch_bounds__(512, 1) void doc_encoder(
    const int* __restrict__ tokens, const float* __restrict__ emb,
    const float* __restrict__ wk_attn, const float* __restrict__ bp_,
    const float* __restrict__ ba_, const float* __restrict__ va_,
    const unsigned short* __restrict__ ws, float* __restrict__ out) {
  __shared__ alignas(16) unsigned char smem[SMEM_BYTES];
  float* miscf = (float*)(smem + MISCB);
  unsigned short* xb = (unsigned short*)(smem + XBOFF);
  unsigned short* kb = (unsigned short*)(smem + KBOFF);
  unsigned short* vb = (unsigned short*)(smem + VBOFF);
  unsigned short* stg = (unsigned short*)(smem + STGOFF);
  unsigned short* Tm = stg;        // [16][304] overlay on buf0 (between B and attn)
  unsigned short* hb = xb;         // overlay after attn
  unsigned short* side = vb;       // overlay after attn
  float* gB = miscf + 384;   // [304]
  float* gw = miscf + 688;   // [304]
  float* gkf = miscf + 992;  // [320]
  float* scp = miscf + 1312; // [2][64]
  float* wsm = miscf + 1440; // [64]

  const int b = blockIdx.x;
  const int tid = threadIdx.x;
  const int lane = tid & 63;
  const int wv = tid >> 6;     // 0..7
  const int wm = wv & 3;       // M tile
  const int wn = wv >> 2;      // job select within chunk
  const int l15 = lane & 15;
  const int lg = lane >> 4;
  const int kofs = lg * 8;
  const int arow = wm * 16 + l15;
  const int cr0 = wm * 16 + lg * 4;
  const float* bobf = ((const float*)ws) + BOBF / 2;
  const float scale = 0.1414213562373095f;
  const f32x4 vzero = {0.f, 0.f, 0.f, 0.f};

  // issue phase-B chunk 0 (jobs 0,1) -> buf0; overlaps with gather below
  stage_pair(ws + KF, ws + KF + 5120, 10, stg, wv, lane);

  // ---- zero inits ----
  for (int i = tid; i < 64 * 4; i += 512) {
    int s = i >> 2, c = 300 + (i & 3);
    kb[s * STR + c] = 0; vb[s * STR + c] = 0;
  }
  if (tid < 20) gkf[300 + tid] = 0.f;
  if (tid < 16) kb[tid] = 0;                 // xb row63 kt9 over-read target

  // ---- gather x = emb[tokens[b]] -> xb bf16 [64][304] ----
  for (int i = tid; i < 64 * 38; i += 512) {
    int s = i / 38, c8 = (i % 38) * 8;
    int tok = tokens[b * 64 + s];
    const float* rp = emb + (size_t)tok * 300;
    short8 v;
    if (c8 + 8 <= 300) {
      f32x4 u0 = *(const f32x4*)(rp + c8);
      f32x4 u1 = *(const f32x4*)(rp + c8 + 4);
#pragma unroll
      for (int j = 0; j < 4; ++j) { v[j] = (short)f2b(u0[j]); v[4 + j] = (short)f2b(u1[j]); }
    } else {
#pragma unroll
      for (int j = 0; j < 8; ++j) v[j] = (c8 + j < 300) ? (short)f2b(rp[c8 + j]) : (short)0;
    }
    *(short8*)&xb[s * STR + c8] = v;
  }
  __syncthreads();   // B0

  short8 ax[10];
#pragma unroll
  for (int kt = 0; kt < 10; ++kt)
    ax[kt] = *(const short8*)&xb[arow * STR + kt * 32 + kofs];

  // ======== Phase B: K(19) V(19) cq(1) = 39 jobs, 20 chunks, DMA dbuf ========
  for (int ch = 0; ch < 20; ++ch) {
    __syncthreads();
    if (ch < 19) {
      int j0 = (ch + 1) * 2;
      const unsigned short* s0 = ws + KF + (size_t)j0 * 5120;
      stage_pair(s0, (j0 + 1 < 39) ? s0 + 5120 : nullptr, 10,
                 stg + ((ch + 1) & 1) * 10240, wv, lane);
    }
    int j = ch * 2 + wn;
    if (j < 39) {
      const unsigned short* bp = stg + (ch & 1) * 10240 + wn * 5120 + lane * 8;
      f32x4 a0 = vzero, a1 = vzero;
#pragma unroll
      for (int k = 0; k < 10; k += 2) {
        a0 = MFMA(ax[k], *(const short8*)(bp + k * 512), a0);
        a1 = MFMA(ax[k + 1], *(const short8*)(bp + (k + 1) * 512), a1);
      }
      f32x4 acc = a0 + a1;
      if (j < 19) {
        int n = j * 16 + l15;
        if (n < 300) {
#pragma unroll
          for (int r = 0; r < 4; ++r) kb[(cr0 + r) * STR + n] = f2b(acc[r]);
        }
      } else if (j < 38) {
        int n = (j - 19) * 16 + l15;
        if (n < 300) {
#pragma unroll
          for (int r = 0; r < 4; ++r) vb[(cr0 + r) * STR + n] = f2b(acc[r]);
        }
      } else if (l15 < 6) {
#pragma unroll
        for (int r = 0; r < 4; ++r) miscf[l15 * 64 + cr0 + r] = acc[r] * scale;
      }
    }
  }
  __syncthreads();

  // ---- alpha softmax (wave h) ----
  if (wv < 6) {
    float* aMh = miscf + wv * 64;
    float x = aMh[lane];
    float m = x;
#pragma unroll
    for (int off = 32; off; off >>= 1) m = fmaxf(m, __shfl_xor(m, off));
    float e = __expf(x - m);
    float ss = e;
#pragma unroll
    for (int off = 32; off; off >>= 1) ss += __shfl_xor(ss, off);
    aMh[lane] = e / ss;
  }
  __syncthreads();

  // ---- Tm zero (rows 6-15, tail, pads) + t_alpha rows 0-5 (buf0 free: last B read was buf1) ----
  for (int i = tid; i < 3056; i += 512) Tm[1824 + i] = 0;   // rows 6-15 + 16 tail
  if (tid < 24) { int rr = tid / 4, cc = 300 + (tid & 3); Tm[rr * STR + cc] = 0; }
  {
    int c = wv * 38 + lane;
    if (lane < 38 && c < 300) {
      float acc[6] = {0.f, 0.f, 0.f, 0.f, 0.f, 0.f};
      for (int s = 0; s < 64; ++s) {
        float xv = b2f(xb[s * STR + c]);
#pragma unroll
        for (int h = 0; h < 6; ++h) acc[h] += miscf[h * 64 + s] * xv;
      }
#pragma unroll
      for (int h = 0; h < 6; ++h) Tm[h * STR + c] = f2b(acc[h]);
    }
  }
  __syncthreads();

  // ---- T1: g = t_alpha @ Wq (19 jobs, direct L2 loads, one per wave round) ----
  {
    short8 aT[10];
#pragma unroll
    for (int kt = 0; kt < 10; ++kt)
      aT[kt] = *(const short8*)&Tm[l15 * STR + kt * 32 + kofs];
    for (int j = wv; j < 19; j += 8) {
      const unsigned short* bp = ws + WQ1 + (size_t)j * 5120 + lane * 8;
      f32x4 a0 = vzero, a1 = vzero;
#pragma unroll
      for (int k = 0; k < 10; k += 2) {
        a0 = MFMA(aT[k], *(const short8*)(bp + k * 512), a0);
        a1 = MFMA(aT[k + 1], *(const short8*)(bp + (k + 1) * 512), a1);
      }
      f32x4 acc = a0 + a1;
      int dt = j * 16 + l15;
#pragma unroll
      for (int r = 0; r < 4; ++r) {
        int h = lg * 4 + r;
        if (h < 6 && dt >= 50 * h && dt < 50 * h + 50) gB[dt] = acc[r];
      }
    }
  }
  __syncthreads();

  // issue attn chunk0 half0 -> buf0 (Tm dead); overlaps with stage C below
  stage_pair(ws + OFC, ws + OFC + 10240, 10, stg, wv, lane);

  if (tid < 300) gw[tid] = gB[tid] * wk_attn[tid];
  __syncthreads();

  // ---- beta softmax (wave h) ----
  if (wv < 6) {
    const int h = wv;
    float* aMh = miscf + h * 64;
    float p = 0.f;
    const unsigned short* krow = kb + lane * STR + 50 * h;
    for (int dd = 0; dd < 50; ++dd) p += gw[50 * h + dd] * b2f(krow[dd]);
    p *= scale;
    float m = p;
#pragma unroll
    for (int off = 32; off; off >>= 1) m = fmaxf(m, __shfl_xor(m, off));
    float e = __expf(p - m);
    float ss = e;
#pragma unroll
    for (int off = 32; off; off >>= 1) ss += __shfl_xor(ss, off);
    aMh[lane] = e / ss;
  }
  __syncthreads();
  // ---- gk = g o (beta^T k) ----
  if (wv < 6 && lane < 50) {
    const int h = wv;
    float gks = 0.f;
    const unsigned short* kcol = kb + 50 * h + lane;
    for (int s = 0; s < 64; ++s) gks += miscf[h * 64 + s] * b2f(kcol[s * STR]);
    gkf[50 * h + lane] = gB[50 * h + lane] * gks;
  }
  __syncthreads();

  // ---- u = gk o v in-place in vb ----
  for (int i = tid; i < 64 * 38; i += 512) {
    int s = i / 38, c8 = (i % 38) * 8;
    short8 vf = *(const short8*)&vb[s * STR + c8];
    short8 uf;
#pragma unroll
    for (int j = 0; j < 8; ++j) {
      int c = c8 + j;
      uf[j] = (c < 300) ? (short)f2b(gkf[c] * b2f((unsigned short)vf[j])) : (short)0;
    }
    *(short8*)&vb[s * STR + c8] = uf;
  }
  short8 ax2[10];
#pragma unroll
  for (int kt = 0; kt < 10; ++kt)
    ax2[kt] = *(const short8*)&xb[arow * STR + kt * 32 + kofs];

  // ======== attn_out = x@Wqo + u@Wro + bobf -> kb  (20 stages = 10 chunks x 2 halves) ========
  {
    f32x4 ac0 = vzero, ac1 = vzero;
    for (int t = 0; t < 20; ++t) {
      __syncthreads();
      if (t < 19) {
        int tn = t + 1, nc = tn >> 1, nh = tn & 1, j0 = nc * 2;
        const unsigned short* s0 = ws + OFC + (size_t)j0 * 10240 + (size_t)nh * 5120;
        stage_pair(s0, (j0 + 1 < 19) ? s0 + 10240 : nullptr, 10,
                   stg + (tn & 1) * 10240, wv, lane);
      }
      int half = t & 1, j = (t >> 1) * 2 + wn;
      if (j < 19) {
        const unsigned short* bp = stg + (t & 1) * 10240 + wn * 5120 + lane * 8;
        if (half == 0) {
          ac0 = vzero; ac1 = vzero;
#pragma unroll
          for (int k = 0; k < 10; k += 2) {
            ac0 = MFMA(ax2[k], *(const short8*)(bp + k * 512), ac0);
            ac1 = MFMA(ax2[k + 1], *(const short8*)(bp + (k + 1) * 512), ac1);
          }
        } else {
          const unsigned short* ub = vb + arow * STR + kofs;
#pragma unroll
          for (int k = 0; k < 10; k += 2) {
            ac0 = MFMA(*(const short8*)(ub + k * 32), *(const short8*)(bp + k * 512), ac0);
            ac1 = MFMA(*(const short8*)(ub + (k + 1) * 32), *(const short8*)(bp + (k + 1) * 512), ac1);
          }
          f32x4 acc = ac0 + ac1;
          int n = j * 16 + l15;
          if (n < 300) {
            float bias = bobf[n];
#pragma unroll
            for (int r = 0; r < 4; ++r) kb[(cr0 + r) * STR + n] = f2b(acc[r] + bias);
          }
        }
      }
    }
  }
  __syncthreads();

  // issue Wp chunk0 -> buf0; zero side pads (h cols 400-415 = side 96-111); load ao
  stage_pair(ws + PFW, ws + PFW + 5120, 10, stg, wv, lane);
  for (int i = tid; i < 64 * 16; i += 512) side[(i >> 4) * SIDE_STR + 96 + (i & 15)] = 0;
  short8 ao[10];
#pragma unroll
  for (int kt = 0; kt < 10; ++kt)
    ao[kt] = *(const short8*)&kb[arow * STR + kt * 32 + kofs];

  // ======== h = attn_out @ Wp + bp -> hb[304] + side[112]  (13 chunks) ========
  for (int ch = 0; ch < 13; ++ch) {
    __syncthreads();
    if (ch < 12) {
      int j0 = (ch + 1) * 2;
      const unsigned short* s0 = ws + PFW + (size_t)j0 * 5120;
      stage_pair(s0, (j0 + 1 < 25) ? s0 + 5120 : nullptr, 10,
                 stg + ((ch + 1) & 1) * 10240, wv, lane);
    }
    int j = ch * 2 + wn;
    if (j < 25) {
      const unsigned short* bp = stg + (ch & 1) * 10240 + wn * 5120 + lane * 8;
      f32x4 a0 = vzero, a1 = vzero;
#pragma unroll
      for (int k = 0; k < 10; k += 2) {
        a0 = MFMA(ao[k], *(const short8*)(bp + k * 512), a0);
        a1 = MFMA(ao[k + 1], *(const short8*)(bp + (k + 1) * 512), a1);
      }
      f32x4 acc = a0 + a1;
      int n = j * 16 + l15;   // < 400
      float bias = bp_[n];
#pragma unroll
      for (int r = 0; r < 4; ++r) {
        unsigned short val = f2b(acc[r] + bias);
        if (n < STR) hb[(cr0 + r) * STR + n] = val;
        else side[(cr0 + r) * SIDE_STR + (n - STR)] = val;
      }
    }
  }
  __syncthreads();

  // issue Wa t0 (chunk0 kt0-6) -> buf0; load ah
  stage_pair(ws + AFW, ws + AFW + 6656, 7, stg, wv, lane);
  short8 ah[13];
#pragma unroll
  for (int kt = 0; kt < 9; ++kt)
    ah[kt] = *(const short8*)&hb[arow * STR + kt * 32 + kofs];
  ah[9] = (lg < 2) ? *(const short8*)&hb[arow * STR + 288 + kofs]
                   : *(const short8*)&side[arow * SIDE_STR + (kofs - 16)];
  ah[10] = *(const short8*)&side[arow * SIDE_STR + 16 + kofs];
  ah[11] = *(const short8*)&side[arow * SIDE_STR + 48 + kofs];
  ah[12] = *(const short8*)&side[arow * SIDE_STR + 80 + kofs];

  // ======== scores = tanh(h@Wa + ba) @ va  (14 stages = 7 chunks x (7kt,6kt)) ========
  float sp[4] = {0.f, 0.f, 0.f, 0.f};
  {
    f32x4 wa0 = vzero, wa1 = vzero;
    for (int t = 0; t < 14; ++t) {
      __syncthreads();
      if (t < 13) {
        int tn = t + 1, nc = tn >> 1, nh = tn & 1, j0 = nc * 2;
        int k0 = nh ? 7 : 0, nk = nh ? 6 : 7;
        const unsigned short* s0 = ws + AFW + (size_t)j0 * 6656 + (size_t)k0 * 512;
        stage_pair(s0, (j0 + 1 < 13) ? s0 + 6656 : nullptr, nk,
                   stg + (tn & 1) * 10240, wv, lane);
      }
      int half = t & 1, j = (t >> 1) * 2 + wn;
      if (j < 13) {
        if (half == 0) {
          const unsigned short* bp = stg + (t & 1) * 10240 + wn * 3584 + lane * 8;
          wa0 = vzero; wa1 = vzero;
          wa0 = MFMA(ah[0], *(const short8*)(bp + 0 * 512), wa0);
          wa1 = MFMA(ah[1], *(const short8*)(bp + 1 * 512), wa1);
          wa0 = MFMA(ah[2], *(const short8*)(bp + 2 * 512), wa0);
          wa1 = MFMA(ah[3], *(const short8*)(bp + 3 * 512), wa1);
          wa0 = MFMA(ah[4], *(const short8*)(bp + 4 * 512), wa0);
          wa1 = MFMA(ah[5], *(const short8*)(bp + 5 * 512), wa1);
          wa0 = MFMA(ah[6], *(const short8*)(bp + 6 * 512), wa0);
        } else {
          const unsigned short* bp = stg + (t & 1) * 10240 + wn * 3072 + lane * 8;
          wa0 = MFMA(ah[7], *(const short8*)(bp + 0 * 512), wa0);
          wa1 = MFMA(ah[8], *(const short8*)(bp + 1 * 512), wa1);
          wa0 = MFMA(ah[9], *(const short8*)(bp + 2 * 512), wa0);
          wa1 = MFMA(ah[10], *(const short8*)(bp + 3 * 512), wa1);
          wa0 = MFMA(ah[11], *(const short8*)(bp + 4 * 512), wa0);
          wa1 = MFMA(ah[12], *(const short8*)(bp + 5 * 512), wa1);
          f32x4 acc = wa0 + wa1;
          int n = j * 16 + l15;
          if (n < 200) {
            float ban = ba_[n], van = va_[n];
#pragma unroll
            for (int r = 0; r < 4; ++r) {
              float x0 = fminf(fmaxf(acc[r] + ban, -15.f), 15.f);
              float t0 = __expf(2.f * x0);
              sp[r] += (t0 - 1.f) / (t0 + 1.f) * van;
            }
          }
        }
      }
    }
  }
#pragma unroll
  for (int off = 1; off < 16; off <<= 1) {
#pragma unroll
    for (int r = 0; r < 4; ++r) sp[r] += __shfl_xor(sp[r], off);
  }
  if (l15 == 0) {
#pragma unroll
    for (int r = 0; r < 4; ++r) scp[wn * 64 + cr0 + r] = sp[r];
  }
  __syncthreads();
  if (wv == 0) {
    float x = scp[lane] + scp[64 + lane];
    float m = x;
#pragma unroll
    for (int off = 32; off; off >>= 1) m = fmaxf(m, __shfl_xor(m, off));
    float e = __expf(x - m);
    float ss = e;
#pragma unroll
    for (int off = 32; off; off >>= 1) ss += __shfl_xor(ss, off);
    wsm[lane] = e / ss;
  }
  __syncthreads();

  // ---- pooled[e] = sum_s wsm[s] h[s][e] ----
  if (tid < 400) {
    float a0 = 0.f, a1 = 0.f, a2 = 0.f, a3 = 0.f;
    for (int s = 0; s < 64; s += 4) {
#pragma unroll
      for (int q = 0; q < 4; ++q) {
        int sq = s + q;
        float hv = (tid < STR) ? b2f(hb[sq * STR + tid])
                               : b2f(side[sq * SIDE_STR + tid - STR]);
        if (q == 0) a0 += wsm[sq] * hv;
        else if (q == 1) a1 += wsm[sq] * hv;
        else if (q == 2) a2 += wsm[sq] * hv;
        else a3 += wsm[sq] * hv;
      }
    }
    out[(size_t)b * 400 + tid] = (a0 + a1) + (a2 + a3);
  }
}

extern "C" void kernel_launch(void* const* d_in, const int* in_sizes, int n_in,
                              void* d_out, int out_size, void* d_ws, size_t ws_size,
                              hipStream_t stream) {
  (void)in_sizes; (void)n_in; (void)out_size; (void)ws_size;
  const int* tokens = (const int*)d_in[0];
  const float* emb = (const float*)d_in[1];
  const float* Wq = (const float*)d_in[2];
  const float* Wk = (const float*)d_in[3];
  const float* Wv = (const float*)d_in[4];
  const float* wq_attn = (const float*)d_in[5];
  const float* wk_attn = (const float*)d_in[6];
  const float* Wr = (const float*)d_in[7];
  const float* br = (const float*)d_in[8];
  const float* Wo = (const float*)d_in[9];
  const float* bo = (const float*)d_in[10];
  const float* Wp = (const float*)d_in[11];
  const float* bp = (const float*)d_in[12];
  const float* Wa = (const float*)d_in[13];
  const float* ba = (const float*)d_in[14];
  const float* va = (const float*)d_in[15];
  unsigned short* wsb = (unsigned short*)d_ws;
  float* out = (float*)d_out;

  prep_weights<<<(PREP_TOTAL + 255) / 256, 256, 0, stream>>>(Wq, Wk, Wv, Wr, Wo, Wp, Wa,
                                                             wq_attn, br, bo, wsb);
  doc_encoder<<<4096, 512, 0, stream>>>(tokens, emb, wk_attn, bp, ba, va, wsb, out);
}